// Round 6
// baseline (275.469 us; speedup 1.0000x reference)
//
#include <hip/hip_runtime.h>
#include <cmath>

#define N_NODES 4096
#define FDIM    256
#define CDIM    40
#define NEDGE   131072
#define CAP     256                  // ELL row capacity (row nnz ~Poisson(64))
#define HBITS   20
#define HSIZE   (1 << HBITS)         // 1M hash slots, load <= 0.125
#define TWO_PI_F 6.28318530717958647692f

typedef __bf16 bf16;
typedef __bf16 bf16x2 __attribute__((ext_vector_type(2)));
typedef __bf16 bf16x4 __attribute__((ext_vector_type(4)));
typedef __bf16 bf16x8 __attribute__((ext_vector_type(8)));
typedef _Float16 f16;
typedef _Float16 f16x2 __attribute__((ext_vector_type(2)));
typedef float  f32x4  __attribute__((ext_vector_type(4)));

static constexpr size_t NF = (size_t)N_NODES * FDIM;      // 1,048,576

// Entry carries PRE-PACKED half2 coefficient pairs:
//   ab = (lr, -li), ba = (li, lr)  so that per complex feature (xr,xi):
//   ar += dot2(ab, x)   ai += dot2(ba, x)   -- one instruction each.
struct __align__(16) Entry { unsigned ab, ba; int col, pad; };

__device__ __forceinline__ unsigned pack_h2(float a, float b) {
    f16x2 h; h[0] = (f16)a; h[1] = (f16)b;
    return __builtin_bit_cast(unsigned, h);
}
__device__ __forceinline__ f16x2 bch2(unsigned u) {
    return __builtin_bit_cast(f16x2, u);
}

// 2-way f16 dot product with f32 accumulate: d = a.x*b.x + a.y*b.y + c
__device__ __forceinline__ float fdot2(f16x2 a, f16x2 b, float c) {
#if __has_builtin(__builtin_amdgcn_fdot2)
    return __builtin_amdgcn_fdot2(a, b, c, false);
#else
    asm("v_dot2_f32_f16 %0, %1, %2, %0" : "+v"(c) : "v"(a), "v"(b));
    return c;
#endif
}

// async global->LDS, 16B per lane, dest = ldsBase + lane*16
__device__ __forceinline__ void gld_lds16(const bf16* g, bf16* s) {
    __builtin_amdgcn_global_load_lds(
        (const __attribute__((address_space(1))) void*)g,
        (__attribute__((address_space(3))) void*)s,
        16, 0, 0);
}

__device__ __forceinline__ unsigned cell_hash(unsigned cell) {
    return (cell * 2654435761u) >> (32 - HBITS);
}

// ---------------------------------------------------------------------------
// 1. Hash-insert edges (duplicate weights summed) + raw row/col degree sums.
// ---------------------------------------------------------------------------
__global__ void hash_insert(const int* __restrict__ edges,
                            const float* __restrict__ ew,
                            int* __restrict__ hkey, float* __restrict__ hval,
                            float* __restrict__ rowsum, float* __restrict__ colsum) {
    int e = blockIdx.x * blockDim.x + threadIdx.x;
    if (e >= NEDGE) return;
    int r = edges[e], c = edges[NEDGE + e];
    float wv = ew[e];
    atomicAdd(rowsum + r, wv);
    atomicAdd(colsum + c, wv);
    unsigned cell = (unsigned)r * N_NODES + c;      // < 2^24
    unsigned h = cell_hash(cell);
    for (;;) {
        int old = atomicCAS(hkey + h, 0, (int)(cell + 1));
        if (old == 0 || old == (int)(cell + 1)) { atomicAdd(hval + h, wv); break; }
        h = (h + 1) & (HSIZE - 1);
    }
}

// ---------------------------------------------------------------------------
// 2. Hash -> ELL, dinv inlined; coefficients packed to half2 pairs.
// ---------------------------------------------------------------------------
__global__ __launch_bounds__(256) void hash_to_ell(
    const int* __restrict__ hkey, const float* __restrict__ hval,
    const float* __restrict__ rowsum, const float* __restrict__ colsum,
    const float* __restrict__ qptr,
    int* __restrict__ cnt, Entry* __restrict__ ent) {
    int h = blockIdx.x * 256 + threadIdx.x;
    int k = hkey[h];
    if (k == 0) return;
    unsigned cell = (unsigned)(k - 1);
    int i = cell >> 12, j = cell & 4095;
    float a = hval[h];
    float b = 0.f;
    bool mirror = false;
    if (i == j) { b = a; mirror = true; }
    else {
        unsigned mcell = (unsigned)j * N_NODES + i;
        unsigned hh = cell_hash(mcell);
        for (;;) {
            int kk = hkey[hh];
            if (kk == (int)(mcell + 1)) { b = hval[hh]; mirror = true; break; }
            if (kk == 0) break;
            hh = (hh + 1) & (HSIZE - 1);
        }
    }
    float di = 0.5f * (rowsum[i] + colsum[i]); if (di == 0.f) di = 1.f;
    float dj = 0.5f * (rowsum[j] + colsum[j]); if (dj == 0.f) dj = 1.f;
    float an = 0.5f * (a + b) / sqrtf(di * dj);
    float s, c;
    sincosf(TWO_PI_F * qptr[0] * (a - b), &s, &c);
    float lr = -an * c;
    float li = an * s;                 // for (i,j); conjugate uses -li
    int pos = atomicAdd(cnt + i, 1);
    if (pos < CAP) {
        Entry en; en.ab = pack_h2(lr, -li); en.ba = pack_h2(li, lr);
        en.col = j; en.pad = 0;
        ent[(size_t)i * CAP + pos] = en;
    }
    if (!mirror) {   // emit conjugate cell (j,i): (lr, -li)
        int pos2 = atomicAdd(cnt + j, 1);
        if (pos2 < CAP) {
            Entry en; en.ab = pack_h2(lr, li); en.ba = pack_h2(-li, lr);
            en.col = i; en.pad = 0;
            ent[(size_t)j * CAP + pos2] = en;
        }
    }
}

// ---------------------------------------------------------------------------
// 3. Cast X -> planar bf16 (wapply input) + interleaved f16 (spmm input)
// ---------------------------------------------------------------------------
__global__ __launch_bounds__(256) void cast_in2(const float* __restrict__ Xr,
                                                const float* __restrict__ Xi,
                                                bf16* __restrict__ Xr16,
                                                bf16* __restrict__ Xi16,
                                                f16* __restrict__ XC) {
    int idx = blockIdx.x * 256 + threadIdx.x;     // n*256+f
    float vr = Xr[idx], vi = Xi[idx];
    Xr16[idx] = (bf16)vr; Xi16[idx] = (bf16)vi;
    ((unsigned*)XC)[idx] = pack_h2(vr, vi);
}

// ---------------------------------------------------------------------------
// 4. Fused weight casts.
// ---------------------------------------------------------------------------
#define NWT (256 * 768)
__global__ __launch_bounds__(256) void cast_weights(
    const float* __restrict__ W1, const float* __restrict__ W2,
    const float* __restrict__ Wc,
    bf16* __restrict__ W1t, bf16* __restrict__ W2t, bf16* __restrict__ Wcb) {
    int idx = blockIdx.x * 256 + threadIdx.x;
    if (idx < 2 * NWT) {
        const float* W = (idx < NWT) ? W1 : W2;
        bf16* Wt = (idx < NWT) ? W1t : W2t;
        int id = (idx < NWT) ? idx : idx - NWT;
        int nout = id / 768, kk = id - nout * 768;
        int o = kk >> 8, k = kk & 255;
        Wt[id] = (bf16)W[((size_t)o * 256 + k) * 256 + nout];
    } else {
        int id = idx - 2 * NWT;
        if (id < 48 * 512) {
            int row = id >> 9, k = id & 511;
            Wcb[id] = (row < CDIM) ? (bf16)Wc[row * 512 + k] : (bf16)0.f;
        }
    }
}

// ---------------------------------------------------------------------------
// 5. Sparse complex SpMM (ELL), v8: ONE WAVE PER ROW. Grid = 1024 blocks x
//    4 independent waves = 4096 rows. No LDS, no barriers, no cross-wave
//    reduction, no idle waves. 8 entries + 8 full-row gathers in flight
//    per wave; fdot2 MAC core on pre-packed half2 coefficients.
// ---------------------------------------------------------------------------
__global__ __launch_bounds__(256) void spmm_k(
    const int* __restrict__ cnt, const Entry* __restrict__ ent,
    const f16* __restrict__ XC,
    const f16* __restrict__ C0C,
    float alpha, float beta,
    bf16* __restrict__ Zr, bf16* __restrict__ Zi, f16* __restrict__ ZC)
{
    const int wave = threadIdx.x >> 6, lane = threadIdx.x & 63;
    const int row = blockIdx.x * 4 + wave;
    int n1 = cnt[row]; if (n1 > CAP) n1 = CAP;
    const Entry* erow = ent + (size_t)row * CAP;

    float ar[4] = {}, ai[4] = {};
    int e = 0;
    // 8 entries + 8 gathers outstanding per wave
    for (; e + 7 < n1; e += 8) {
        uint4 er[8];
        #pragma unroll
        for (int u = 0; u < 8; ++u)
            er[u] = *(const uint4*)&erow[e + u];
        uint4 xv[8];
        #pragma unroll
        for (int u = 0; u < 8; ++u)
            xv[u] = *(const uint4*)&XC[(size_t)(er[u].z & 4095) * 512 + lane * 8];
        #pragma unroll
        for (int u = 0; u < 8; ++u) {
            f16x2 ab = bch2(er[u].x), ba = bch2(er[u].y);
            ar[0] = fdot2(ab, bch2(xv[u].x), ar[0]); ai[0] = fdot2(ba, bch2(xv[u].x), ai[0]);
            ar[1] = fdot2(ab, bch2(xv[u].y), ar[1]); ai[1] = fdot2(ba, bch2(xv[u].y), ai[1]);
            ar[2] = fdot2(ab, bch2(xv[u].z), ar[2]); ai[2] = fdot2(ba, bch2(xv[u].z), ai[2]);
            ar[3] = fdot2(ab, bch2(xv[u].w), ar[3]); ai[3] = fdot2(ba, bch2(xv[u].w), ai[3]);
        }
    }
    for (; e < n1; ++e) {
        uint4 er = *(const uint4*)&erow[e];
        uint4 x0 = *(const uint4*)&XC[(size_t)(er.z & 4095) * 512 + lane * 8];
        f16x2 ab = bch2(er.x), ba = bch2(er.y);
        ar[0] = fdot2(ab, bch2(x0.x), ar[0]); ai[0] = fdot2(ba, bch2(x0.x), ai[0]);
        ar[1] = fdot2(ab, bch2(x0.y), ar[1]); ai[1] = fdot2(ba, bch2(x0.y), ai[1]);
        ar[2] = fdot2(ab, bch2(x0.z), ar[2]); ai[2] = fdot2(ba, bch2(x0.z), ai[2]);
        ar[3] = fdot2(ab, bch2(x0.w), ar[3]); ai[3] = fdot2(ba, bch2(x0.w), ai[3]);
    }

    float vr[4], vi[4];
    if (beta != 0.f) {
        uint4 c0 = *(const uint4*)&C0C[(size_t)row * 512 + lane * 8];
        f16x2 h0 = bch2(c0.x), h1 = bch2(c0.y), h2 = bch2(c0.z), h3 = bch2(c0.w);
        vr[0] = alpha * ar[0] + beta * (float)h0[0];
        vi[0] = alpha * ai[0] + beta * (float)h0[1];
        vr[1] = alpha * ar[1] + beta * (float)h1[0];
        vi[1] = alpha * ai[1] + beta * (float)h1[1];
        vr[2] = alpha * ar[2] + beta * (float)h2[0];
        vi[2] = alpha * ai[2] + beta * (float)h2[1];
        vr[3] = alpha * ar[3] + beta * (float)h3[0];
        vi[3] = alpha * ai[3] + beta * (float)h3[1];
    } else {
        #pragma unroll
        for (int c = 0; c < 4; ++c) { vr[c] = alpha * ar[c]; vi[c] = alpha * ai[c]; }
    }
    size_t base = (size_t)row * FDIM + lane * 4;
    bf16x4 pr, pi;
    #pragma unroll
    for (int c = 0; c < 4; ++c) { pr[c] = (bf16)vr[c]; pi[c] = (bf16)vi[c]; }
    *(bf16x4*)&Zr[base] = pr;
    *(bf16x4*)&Zi[base] = pi;
    if (ZC) {
        uint4 o;
        o.x = pack_h2(vr[0], vi[0]);
        o.y = pack_h2(vr[1], vi[1]);
        o.z = pack_h2(vr[2], vi[2]);
        o.w = pack_h2(vr[3], vi[3]);
        *(uint4*)&ZC[(size_t)row * 512 + lane * 8] = o;
    }
}

// ---------------------------------------------------------------------------
// 6. wapply via MFMA (unchanged from round 5).
// ---------------------------------------------------------------------------
__global__ __launch_bounds__(256) void wapply_mfma(
    const bf16* __restrict__ Z0r, const bf16* __restrict__ Z0i,
    const bf16* __restrict__ Z1r, const bf16* __restrict__ Z1i,
    const bf16* __restrict__ Z2r, const bf16* __restrict__ Z2i,
    const bf16* __restrict__ Wt,      // [256][768]
    const float* __restrict__ bias,   // [256]
    bf16* __restrict__ O16r_r, bf16* __restrict__ O16r_i,
    f16* __restrict__ OC)
{
    __shared__ __align__(16) bf16 sZr[64 * 32];
    __shared__ __align__(16) bf16 sZi[64 * 32];
    __shared__ __align__(16) bf16 sW [64 * 32];

    const int tid  = threadIdx.x;
    const int wave = tid >> 6;
    const int lane = tid & 63;
    const int rowBase = blockIdx.y * 64;
    const int colBase = blockIdx.x * 64;

    const int srow = lane >> 2;
    const int skc  = (lane & 3) * 8;

    f32x4 accSr[2][2] = {}, accSi[2][2] = {};
    const int wm = wave & 1, wn = wave >> 1;
    const int fr = lane & 15;
    const int fk = (lane >> 4) * 8;

    for (int kb = 0; kb < 3 * FDIM; kb += 32) {
        int order = kb >> 8;
        int kloc  = kb & 255;
        if (wave == 0 || wave == 1) {
            const bf16* z;
            if (wave == 0) z = (order == 0) ? Z0r : (order == 1) ? Z1r : Z2r;
            else           z = (order == 0) ? Z0i : (order == 1) ? Z1i : Z2i;
            bf16* s = (wave == 0) ? sZr : sZi;
            const bf16* g = z + (size_t)(rowBase + srow) * FDIM + kloc + skc;
            #pragma unroll
            for (int t = 0; t < 4; ++t)
                gld_lds16(g + (size_t)t * 16 * FDIM, s + t * 512);
        } else if (wave == 2) {
            const bf16* g = Wt + (size_t)(colBase + srow) * 768 + kb + skc;
            #pragma unroll
            for (int t = 0; t < 4; ++t)
                gld_lds16(g + (size_t)t * 16 * 768, sW + t * 512);
        }
        __syncthreads();

        bf16x8 zr[2], zi[2], wv[2];
        #pragma unroll
        for (int m = 0; m < 2; ++m) {
            int r = wm * 32 + m * 16 + fr;
            zr[m] = *(const bf16x8*)&sZr[r * 32 + fk];
            zi[m] = *(const bf16x8*)&sZi[r * 32 + fk];
        }
        #pragma unroll
        for (int n = 0; n < 2; ++n) {
            int c = wn * 32 + n * 16 + fr;
            wv[n] = *(const bf16x8*)&sW[c * 32 + fk];
        }
        #pragma unroll
        for (int m = 0; m < 2; ++m)
            #pragma unroll
            for (int n = 0; n < 2; ++n) {
                accSr[m][n] = __builtin_amdgcn_mfma_f32_16x16x32_bf16(zr[m], wv[n], accSr[m][n], 0, 0, 0);
                accSi[m][n] = __builtin_amdgcn_mfma_f32_16x16x32_bf16(zi[m], wv[n], accSi[m][n], 0, 0, 0);
            }
        __syncthreads();
    }

    #pragma unroll
    for (int m = 0; m < 2; ++m)
        #pragma unroll
        for (int n = 0; n < 2; ++n) {
            int row0 = rowBase + wm * 32 + m * 16 + (lane >> 4) * 4;
            int col  = colBase + wn * 32 + n * 16 + (lane & 15);
            float bv = bias[col];
            #pragma unroll
            for (int r = 0; r < 4; ++r) {
                float vr = bv - accSi[m][n][r];
                float vi = bv + accSr[m][n][r];
                int row = row0 + r;
                size_t idx = (size_t)row * FDIM + col;
                if (O16r_r) {
                    O16r_r[idx] = (bf16)vr; O16r_i[idx] = (bf16)vi;
                }
                if (OC) {
                    ((unsigned*)OC)[idx] = pack_h2(vr, vi);
                }
            }
        }
}

// ---------------------------------------------------------------------------
// 7. Head via MFMA + fused log_softmax (unchanged).
// ---------------------------------------------------------------------------
__global__ __launch_bounds__(256) void head_mfma(
    const bf16* __restrict__ Yrb,
    const bf16* __restrict__ Yib,
    const bf16* __restrict__ Wcb,
    const float* __restrict__ bc,
    float* __restrict__ out)          // [4096][40]
{
    __shared__ __align__(16) bf16 sY[64][72];
    __shared__ __align__(16) bf16 sW[48][72];
    __shared__ float sS[64][52];

    const int tid  = threadIdx.x;
    const int wave = tid >> 6;
    const int lane = tid & 63;
    const int r0 = blockIdx.x * 64;

    f32x4 acc[3] = {};

    for (int kb = 0; kb < 512; kb += 64) {
        const bf16* src = (kb < 256) ? Yrb : Yib;
        const int koff = kb & 255;
        #pragma unroll
        for (int e = 0; e < 2; ++e) {
            int idx = tid + e * 256;             // 0..511
            int rr = idx >> 3, kk = (idx & 7) * 8;
            *(bf16x8*)&sY[rr][kk] =
                *(const bf16x8*)&src[(size_t)(r0 + rr) * FDIM + koff + kk];
        }
        #pragma unroll
        for (int e = 0; e < 2; ++e) {
            int idx = tid + e * 256;             // need 0..383
            if (idx < 384) {
                int rr = idx >> 3, kk = (idx & 7) * 8;
                *(bf16x8*)&sW[rr][kk] =
                    *(const bf16x8*)&Wcb[(size_t)rr * 512 + kb + kk];
            }
        }
        __syncthreads();
        #pragma unroll
        for (int ks = 0; ks < 2; ++ks) {
            bf16x8 a = *(const bf16x8*)&sY[wave * 16 + (lane & 15)][ks * 32 + (lane >> 4) * 8];
            #pragma unroll
            for (int n = 0; n < 3; ++n) {
                bf16x8 b = *(const bf16x8*)&sW[n * 16 + (lane & 15)][ks * 32 + (lane >> 4) * 8];
                acc[n] = __builtin_amdgcn_mfma_f32_16x16x32_bf16(a, b, acc[n], 0, 0, 0);
            }
        }
        __syncthreads();
    }

    #pragma unroll
    for (int n = 0; n < 3; ++n) {
        int col = n * 16 + (lane & 15);
        int rloc = wave * 16 + (lane >> 4) * 4;
        #pragma unroll
        for (int r = 0; r < 4; ++r)
            sS[rloc + r][col] = acc[n][r];
    }
    __syncthreads();

    if (tid < 64) {
        float mx = -INFINITY;
        #pragma unroll 8
        for (int c = 0; c < CDIM; ++c) {
            float lv = sS[tid][c] + bc[c];
            sS[tid][c] = lv;
            mx = fmaxf(mx, lv);
        }
        float se = 0.f;
        #pragma unroll 8
        for (int c = 0; c < CDIM; ++c) se += expf(sS[tid][c] - mx);
        float lse = mx + logf(se);
        #pragma unroll 8
        for (int c = 0; c < CDIM; ++c)
            out[(size_t)(r0 + tid) * CDIM + c] = sS[tid][c] - lse;
    }
}

// ---------------------------------------------------------------------------
// Launcher
// ---------------------------------------------------------------------------
extern "C" void kernel_launch(void* const* d_in, const int* in_sizes, int n_in,
                              void* d_out, int out_size, void* d_ws, size_t ws_size,
                              hipStream_t stream) {
    const float* real = (const float*)d_in[0];
    const float* imag = (const float*)d_in[1];
    const int*   edges = (const int*)d_in[2];
    const float* q    = (const float*)d_in[3];
    const float* ew   = (const float*)d_in[4];
    const float* W1   = (const float*)d_in[5];
    const float* b1   = (const float*)d_in[6];
    const float* W2   = (const float*)d_in[7];
    const float* b2   = (const float*)d_in[8];
    const float* Wc   = (const float*)d_in[9];
    const float* bc   = (const float*)d_in[10];
    float* out = (float*)d_out;

    // ---- workspace carve-up ----
    char* w = (char*)d_ws;
    int*      hkey   = (int*)w;   w += (size_t)HSIZE * 4;       // 4 MB
    float*    hval   = (float*)w; w += (size_t)HSIZE * 4;       // 4 MB
    int*      cnt    = (int*)w;   w += N_NODES * 4;
    float*    rowsum = (float*)w; w += N_NODES * 4;
    float*    colsum = (float*)w; w += N_NODES * 4;
    size_t zero_bytes = (size_t)((char*)w - (char*)d_ws);
    // Non-zeroed:
    Entry* ent  = (Entry*)w; w += (size_t)N_NODES * CAP * 16;   // 16 MB
    bf16* Xr16 = (bf16*)w; w += NF * 2;
    bf16* Xi16 = (bf16*)w; w += NF * 2;
    f16*  XC   = (f16*)w;  w += NF * 4;                         // interleaved f16
    bf16* Z1r  = (bf16*)w; w += NF * 2;
    bf16* Z1i  = (bf16*)w; w += NF * 2;
    f16*  Z1C  = (f16*)w;  w += NF * 4;
    bf16* Z2r  = (bf16*)w; w += NF * 2;
    bf16* Z2i  = (bf16*)w; w += NF * 2;
    bf16* Y1rb = (bf16*)w; w += NF * 2;
    bf16* Y1ib = (bf16*)w; w += NF * 2;
    f16*  Y1C  = (f16*)w;  w += NF * 4;
    bf16* Y2rb = (bf16*)w; w += NF * 2;
    bf16* Y2ib = (bf16*)w; w += NF * 2;
    bf16* W1t  = (bf16*)w; w += 256 * 768 * 2;
    bf16* W2t  = (bf16*)w; w += 256 * 768 * 2;
    bf16* Wcb  = (bf16*)w; w += 48 * 512 * 2;

    hipMemsetAsync(d_ws, 0, zero_bytes, stream);

    // ---- build sparse L (hash -> ELL) ----
    hash_insert<<<(NEDGE + 255) / 256, 256, 0, stream>>>(edges, ew, hkey, hval,
                                                         rowsum, colsum);
    hash_to_ell<<<HSIZE / 256, 256, 0, stream>>>(hkey, hval, rowsum, colsum,
                                                 q, cnt, ent);

    // ---- casts ----
    cast_in2<<<NF / 256, 256, 0, stream>>>(real, imag, Xr16, Xi16, XC);
    cast_weights<<<(2 * NWT + 48 * 512 + 255) / 256, 256, 0, stream>>>(
        W1, W2, Wc, W1t, W2t, Wcb);

    dim3 gW(FDIM / 64, N_NODES / 64);   // (4, 64)
    const int gS = N_NODES / 4;         // one wave per row, 4 rows/block

    // ---- Layer 1 ----
    spmm_k<<<gS, 256, 0, stream>>>(cnt, ent, XC, nullptr,
                                   1.f, 0.f, Z1r, Z1i, Z1C);
    spmm_k<<<gS, 256, 0, stream>>>(cnt, ent, Z1C, XC,
                                   2.f, -1.f, Z2r, Z2i, nullptr);
    wapply_mfma<<<gW, 256, 0, stream>>>(Xr16, Xi16, Z1r, Z1i, Z2r, Z2i,
                                        W1t, b1,
                                        Y1rb, Y1ib,
                                        Y1C);

    // ---- Layer 2 ----
    spmm_k<<<gS, 256, 0, stream>>>(cnt, ent, Y1C, nullptr,
                                   1.f, 0.f, Z1r, Z1i, Z1C);
    spmm_k<<<gS, 256, 0, stream>>>(cnt, ent, Z1C, Y1C,
                                   2.f, -1.f, Z2r, Z2i, nullptr);
    wapply_mfma<<<gW, 256, 0, stream>>>(Y1rb, Y1ib, Z1r, Z1i, Z2r, Z2i,
                                        W2t, b2,
                                        Y2rb, Y2ib,
                                        nullptr);

    // ---- Head ----
    head_mfma<<<64, 256, 0, stream>>>(Y2rb, Y2ib, Wcb, bc, out);
}

// Round 7
// 271.625 us; speedup vs baseline: 1.0142x; 1.0142x over previous
//
#include <hip/hip_runtime.h>
#include <cmath>

#define N_NODES 4096
#define FDIM    256
#define CDIM    40
#define NEDGE   131072
#define CAP     256                  // ELL row capacity (row nnz ~Poisson(64))
#define HBITS   19
#define HSIZE   (1 << HBITS)         // 512K hash slots, load <= 0.25
#define TWO_PI_F 6.28318530717958647692f

typedef __bf16 bf16;
typedef __bf16 bf16x2 __attribute__((ext_vector_type(2)));
typedef __bf16 bf16x4 __attribute__((ext_vector_type(4)));
typedef __bf16 bf16x8 __attribute__((ext_vector_type(8)));
typedef _Float16 f16;
typedef _Float16 f16x2 __attribute__((ext_vector_type(2)));
typedef float  f32x4  __attribute__((ext_vector_type(4)));

static constexpr size_t NF = (size_t)N_NODES * FDIM;      // 1,048,576

// Entry carries PRE-PACKED half2 coefficient pairs:
//   ab = (lr, -li), ba = (li, lr)  so that per complex feature (xr,xi):
//   ar += dot2(ab, x)   ai += dot2(ba, x)   -- one instruction each.
struct __align__(16) Entry { unsigned ab, ba; int col, pad; };

__device__ __forceinline__ unsigned pack_h2(float a, float b) {
    f16x2 h; h[0] = (f16)a; h[1] = (f16)b;
    return __builtin_bit_cast(unsigned, h);
}
__device__ __forceinline__ f16x2 bch2(unsigned u) {
    return __builtin_bit_cast(f16x2, u);
}

// 2-way f16 dot product with f32 accumulate: d = a.x*b.x + a.y*b.y + c
__device__ __forceinline__ float fdot2(f16x2 a, f16x2 b, float c) {
#if __has_builtin(__builtin_amdgcn_fdot2)
    return __builtin_amdgcn_fdot2(a, b, c, false);
#else
    asm("v_dot2_f32_f16 %0, %1, %2, %0" : "+v"(c) : "v"(a), "v"(b));
    return c;
#endif
}

// async global->LDS, 16B per lane, dest = ldsBase + lane*16
__device__ __forceinline__ void gld_lds16(const bf16* g, bf16* s) {
    __builtin_amdgcn_global_load_lds(
        (const __attribute__((address_space(1))) void*)g,
        (__attribute__((address_space(3))) void*)s,
        16, 0, 0);
}

__device__ __forceinline__ unsigned cell_hash(unsigned cell) {
    return (cell * 2654435761u) >> (32 - HBITS);
}

// ---------------------------------------------------------------------------
// 1. Hash-insert edges (duplicate weights summed) + raw row/col degree sums.
// ---------------------------------------------------------------------------
__global__ void hash_insert(const int* __restrict__ edges,
                            const float* __restrict__ ew,
                            int* __restrict__ hkey, float* __restrict__ hval,
                            float* __restrict__ rowsum, float* __restrict__ colsum) {
    int e = blockIdx.x * blockDim.x + threadIdx.x;
    if (e >= NEDGE) return;
    int r = edges[e], c = edges[NEDGE + e];
    float wv = ew[e];
    atomicAdd(rowsum + r, wv);
    atomicAdd(colsum + c, wv);
    unsigned cell = (unsigned)r * N_NODES + c;      // < 2^24
    unsigned h = cell_hash(cell);
    for (;;) {
        int old = atomicCAS(hkey + h, 0, (int)(cell + 1));
        if (old == 0 || old == (int)(cell + 1)) { atomicAdd(hval + h, wv); break; }
        h = (h + 1) & (HSIZE - 1);
    }
}

// ---------------------------------------------------------------------------
// 2. Hash -> ELL, dinv inlined; coefficients packed to half2 pairs.
// ---------------------------------------------------------------------------
__global__ __launch_bounds__(256) void hash_to_ell(
    const int* __restrict__ hkey, const float* __restrict__ hval,
    const float* __restrict__ rowsum, const float* __restrict__ colsum,
    const float* __restrict__ qptr,
    int* __restrict__ cnt, Entry* __restrict__ ent) {
    int h = blockIdx.x * 256 + threadIdx.x;
    int k = hkey[h];
    if (k == 0) return;
    unsigned cell = (unsigned)(k - 1);
    int i = cell >> 12, j = cell & 4095;
    float a = hval[h];
    float b = 0.f;
    bool mirror = false;
    if (i == j) { b = a; mirror = true; }
    else {
        unsigned mcell = (unsigned)j * N_NODES + i;
        unsigned hh = cell_hash(mcell);
        for (;;) {
            int kk = hkey[hh];
            if (kk == (int)(mcell + 1)) { b = hval[hh]; mirror = true; break; }
            if (kk == 0) break;
            hh = (hh + 1) & (HSIZE - 1);
        }
    }
    float di = 0.5f * (rowsum[i] + colsum[i]); if (di == 0.f) di = 1.f;
    float dj = 0.5f * (rowsum[j] + colsum[j]); if (dj == 0.f) dj = 1.f;
    float an = 0.5f * (a + b) / sqrtf(di * dj);
    float s, c;
    sincosf(TWO_PI_F * qptr[0] * (a - b), &s, &c);
    float lr = -an * c;
    float li = an * s;                 // for (i,j); conjugate uses -li
    int pos = atomicAdd(cnt + i, 1);
    if (pos < CAP) {
        Entry en; en.ab = pack_h2(lr, -li); en.ba = pack_h2(li, lr);
        en.col = j; en.pad = 0;
        ent[(size_t)i * CAP + pos] = en;
    }
    if (!mirror) {   // emit conjugate cell (j,i): (lr, -li)
        int pos2 = atomicAdd(cnt + j, 1);
        if (pos2 < CAP) {
            Entry en; en.ab = pack_h2(lr, li); en.ba = pack_h2(-li, lr);
            en.col = i; en.pad = 0;
            ent[(size_t)j * CAP + pos2] = en;
        }
    }
}

// ---------------------------------------------------------------------------
// 3. Merged casts: blocks [0,4096) cast X -> planar bf16 + interleaved f16;
//    blocks [4096, 5728) cast W1/W2 -> transposed bf16 and Wc -> padded bf16.
// ---------------------------------------------------------------------------
#define NWT (256 * 768)
#define CAST_W_BLOCKS ((2 * NWT + 48 * 512) / 256)   // 1632
__global__ __launch_bounds__(256) void cast_all(
    const float* __restrict__ Xr, const float* __restrict__ Xi,
    const float* __restrict__ W1, const float* __restrict__ W2,
    const float* __restrict__ Wc,
    bf16* __restrict__ Xr16, bf16* __restrict__ Xi16, f16* __restrict__ XC,
    bf16* __restrict__ W1t, bf16* __restrict__ W2t, bf16* __restrict__ Wcb) {
    int bid = blockIdx.x;
    if (bid < (int)(NF / 256)) {
        int idx = bid * 256 + threadIdx.x;            // n*256+f
        float vr = Xr[idx], vi = Xi[idx];
        Xr16[idx] = (bf16)vr; Xi16[idx] = (bf16)vi;
        ((unsigned*)XC)[idx] = pack_h2(vr, vi);
    } else {
        int idx = (bid - (int)(NF / 256)) * 256 + threadIdx.x;
        if (idx < 2 * NWT) {
            const float* W = (idx < NWT) ? W1 : W2;
            bf16* Wt = (idx < NWT) ? W1t : W2t;
            int id = (idx < NWT) ? idx : idx - NWT;
            int nout = id / 768, kk = id - nout * 768;
            int o = kk >> 8, k = kk & 255;
            Wt[id] = (bf16)W[((size_t)o * 256 + k) * 256 + nout];
        } else {
            int id = idx - 2 * NWT;
            int row = id >> 9, k = id & 511;
            Wcb[id] = (row < CDIM) ? (bf16)Wc[row * 512 + k] : (bf16)0.f;
        }
    }
}

// ---------------------------------------------------------------------------
// 5. Sparse complex SpMM (ELL) -- round-5 version verbatim (best measured):
//    one block (4 waves) per row, entries wave-strided, 4 gathers in flight,
//    fdot2 MAC core on pre-packed half2 coefficients.
// ---------------------------------------------------------------------------
__global__ __launch_bounds__(256) void spmm_k(
    const int* __restrict__ cnt, const Entry* __restrict__ ent,
    const f16* __restrict__ XC,
    const f16* __restrict__ C0C,
    float alpha, float beta,
    bf16* __restrict__ Zr, bf16* __restrict__ Zi, f16* __restrict__ ZC)
{
    __shared__ f32x4 redR[3][64];
    __shared__ f32x4 redI[3][64];

    const int wave = threadIdx.x >> 6, lane = threadIdx.x & 63;
    const int row = blockIdx.x;
    int n1 = cnt[row]; if (n1 > CAP) n1 = CAP;
    const Entry* erow = ent + (size_t)row * CAP;

    float ar[4] = {}, ai[4] = {};
    int e = wave;
    for (; e + 12 < n1; e += 16) {
        Entry e0 = erow[e];
        Entry e1 = erow[e + 4];
        Entry e2 = erow[e + 8];
        Entry e3 = erow[e + 12];
        uint4 x0 = *(const uint4*)&XC[(size_t)(e0.col & 4095) * 512 + lane * 8];
        uint4 x1 = *(const uint4*)&XC[(size_t)(e1.col & 4095) * 512 + lane * 8];
        uint4 x2 = *(const uint4*)&XC[(size_t)(e2.col & 4095) * 512 + lane * 8];
        uint4 x3 = *(const uint4*)&XC[(size_t)(e3.col & 4095) * 512 + lane * 8];
        {
            f16x2 ab = bch2(e0.ab), ba = bch2(e0.ba);
            ar[0] = fdot2(ab, bch2(x0.x), ar[0]); ai[0] = fdot2(ba, bch2(x0.x), ai[0]);
            ar[1] = fdot2(ab, bch2(x0.y), ar[1]); ai[1] = fdot2(ba, bch2(x0.y), ai[1]);
            ar[2] = fdot2(ab, bch2(x0.z), ar[2]); ai[2] = fdot2(ba, bch2(x0.z), ai[2]);
            ar[3] = fdot2(ab, bch2(x0.w), ar[3]); ai[3] = fdot2(ba, bch2(x0.w), ai[3]);
        }
        {
            f16x2 ab = bch2(e1.ab), ba = bch2(e1.ba);
            ar[0] = fdot2(ab, bch2(x1.x), ar[0]); ai[0] = fdot2(ba, bch2(x1.x), ai[0]);
            ar[1] = fdot2(ab, bch2(x1.y), ar[1]); ai[1] = fdot2(ba, bch2(x1.y), ai[1]);
            ar[2] = fdot2(ab, bch2(x1.z), ar[2]); ai[2] = fdot2(ba, bch2(x1.z), ai[2]);
            ar[3] = fdot2(ab, bch2(x1.w), ar[3]); ai[3] = fdot2(ba, bch2(x1.w), ai[3]);
        }
        {
            f16x2 ab = bch2(e2.ab), ba = bch2(e2.ba);
            ar[0] = fdot2(ab, bch2(x2.x), ar[0]); ai[0] = fdot2(ba, bch2(x2.x), ai[0]);
            ar[1] = fdot2(ab, bch2(x2.y), ar[1]); ai[1] = fdot2(ba, bch2(x2.y), ai[1]);
            ar[2] = fdot2(ab, bch2(x2.z), ar[2]); ai[2] = fdot2(ba, bch2(x2.z), ai[2]);
            ar[3] = fdot2(ab, bch2(x2.w), ar[3]); ai[3] = fdot2(ba, bch2(x2.w), ai[3]);
        }
        {
            f16x2 ab = bch2(e3.ab), ba = bch2(e3.ba);
            ar[0] = fdot2(ab, bch2(x3.x), ar[0]); ai[0] = fdot2(ba, bch2(x3.x), ai[0]);
            ar[1] = fdot2(ab, bch2(x3.y), ar[1]); ai[1] = fdot2(ba, bch2(x3.y), ai[1]);
            ar[2] = fdot2(ab, bch2(x3.z), ar[2]); ai[2] = fdot2(ba, bch2(x3.z), ai[2]);
            ar[3] = fdot2(ab, bch2(x3.w), ar[3]); ai[3] = fdot2(ba, bch2(x3.w), ai[3]);
        }
    }
    for (; e < n1; e += 4) {
        Entry e0 = erow[e];
        uint4 x0 = *(const uint4*)&XC[(size_t)(e0.col & 4095) * 512 + lane * 8];
        f16x2 ab = bch2(e0.ab), ba = bch2(e0.ba);
        ar[0] = fdot2(ab, bch2(x0.x), ar[0]); ai[0] = fdot2(ba, bch2(x0.x), ai[0]);
        ar[1] = fdot2(ab, bch2(x0.y), ar[1]); ai[1] = fdot2(ba, bch2(x0.y), ai[1]);
        ar[2] = fdot2(ab, bch2(x0.z), ar[2]); ai[2] = fdot2(ba, bch2(x0.z), ai[2]);
        ar[3] = fdot2(ab, bch2(x0.w), ar[3]); ai[3] = fdot2(ba, bch2(x0.w), ai[3]);
    }

    if (wave != 0) {
        f32x4 r, i;
        #pragma unroll
        for (int c = 0; c < 4; ++c) { r[c] = ar[c]; i[c] = ai[c]; }
        redR[wave - 1][lane] = r;
        redI[wave - 1][lane] = i;
    }
    __syncthreads();
    if (wave != 0) return;

    #pragma unroll
    for (int w = 0; w < 3; ++w) {
        f32x4 r = redR[w][lane], i = redI[w][lane];
        #pragma unroll
        for (int c = 0; c < 4; ++c) { ar[c] += r[c]; ai[c] += i[c]; }
    }

    float vr[4], vi[4];
    if (beta != 0.f) {
        uint4 c0 = *(const uint4*)&C0C[(size_t)row * 512 + lane * 8];
        f16x2 h0 = bch2(c0.x), h1 = bch2(c0.y), h2 = bch2(c0.z), h3 = bch2(c0.w);
        vr[0] = alpha * ar[0] + beta * (float)h0[0];
        vi[0] = alpha * ai[0] + beta * (float)h0[1];
        vr[1] = alpha * ar[1] + beta * (float)h1[0];
        vi[1] = alpha * ai[1] + beta * (float)h1[1];
        vr[2] = alpha * ar[2] + beta * (float)h2[0];
        vi[2] = alpha * ai[2] + beta * (float)h2[1];
        vr[3] = alpha * ar[3] + beta * (float)h3[0];
        vi[3] = alpha * ai[3] + beta * (float)h3[1];
    } else {
        #pragma unroll
        for (int c = 0; c < 4; ++c) { vr[c] = alpha * ar[c]; vi[c] = alpha * ai[c]; }
    }
    size_t base = (size_t)row * FDIM + lane * 4;
    bf16x4 pr, pi;
    #pragma unroll
    for (int c = 0; c < 4; ++c) { pr[c] = (bf16)vr[c]; pi[c] = (bf16)vi[c]; }
    *(bf16x4*)&Zr[base] = pr;
    *(bf16x4*)&Zi[base] = pi;
    if (ZC) {
        uint4 o;
        o.x = pack_h2(vr[0], vi[0]);
        o.y = pack_h2(vr[1], vi[1]);
        o.z = pack_h2(vr[2], vi[2]);
        o.w = pack_h2(vr[3], vi[3]);
        *(uint4*)&ZC[(size_t)row * 512 + lane * 8] = o;
    }
}

// ---------------------------------------------------------------------------
// 6. wapply via MFMA, v2: 32-row x 64-col tiles -> grid (4,128) = 512 blocks
//    = 2 blocks/CU (was 1), so two blocks interleave across staging barriers.
//    Per wave: 16-col strip, 2 row-frags, 4 MFMA per K-step. Same total MFMA.
// ---------------------------------------------------------------------------
__global__ __launch_bounds__(256) void wapply_mfma(
    const bf16* __restrict__ Z0r, const bf16* __restrict__ Z0i,
    const bf16* __restrict__ Z1r, const bf16* __restrict__ Z1i,
    const bf16* __restrict__ Z2r, const bf16* __restrict__ Z2i,
    const bf16* __restrict__ Wt,      // [256][768]
    const float* __restrict__ bias,   // [256]
    bf16* __restrict__ O16r_r, bf16* __restrict__ O16r_i,
    f16* __restrict__ OC)
{
    __shared__ __align__(16) bf16 sZr[32 * 32];
    __shared__ __align__(16) bf16 sZi[32 * 32];
    __shared__ __align__(16) bf16 sW [64 * 32];

    const int tid  = threadIdx.x;
    const int wave = tid >> 6;
    const int lane = tid & 63;
    const int rowBase = blockIdx.y * 32;
    const int colBase = blockIdx.x * 64;

    const int srow = lane >> 2;          // 0..15
    const int skc  = (lane & 3) * 8;

    f32x4 accSr[2] = {}, accSi[2] = {};
    const int fr = lane & 15;
    const int fk = (lane >> 4) * 8;

    for (int kb = 0; kb < 3 * FDIM; kb += 32) {
        int order = kb >> 8;
        int kloc  = kb & 255;
        if (wave == 0 || wave == 1) {
            const bf16* z;
            if (wave == 0) z = (order == 0) ? Z0r : (order == 1) ? Z1r : Z2r;
            else           z = (order == 0) ? Z0i : (order == 1) ? Z1i : Z2i;
            bf16* s = (wave == 0) ? sZr : sZi;
            const bf16* g = z + (size_t)(rowBase + srow) * FDIM + kloc + skc;
            #pragma unroll
            for (int t = 0; t < 2; ++t)
                gld_lds16(g + (size_t)t * 16 * FDIM, s + t * 512);
        } else if (wave == 2) {
            const bf16* g = Wt + (size_t)(colBase + srow) * 768 + kb + skc;
            #pragma unroll
            for (int t = 0; t < 4; ++t)
                gld_lds16(g + (size_t)t * 16 * 768, sW + t * 512);
        }
        __syncthreads();

        bf16x8 zr[2], zi[2], wv;
        #pragma unroll
        for (int m = 0; m < 2; ++m) {
            int r = m * 16 + fr;
            zr[m] = *(const bf16x8*)&sZr[r * 32 + fk];
            zi[m] = *(const bf16x8*)&sZi[r * 32 + fk];
        }
        wv = *(const bf16x8*)&sW[(wave * 16 + fr) * 32 + fk];
        #pragma unroll
        for (int m = 0; m < 2; ++m) {
            accSr[m] = __builtin_amdgcn_mfma_f32_16x16x32_bf16(zr[m], wv, accSr[m], 0, 0, 0);
            accSi[m] = __builtin_amdgcn_mfma_f32_16x16x32_bf16(zi[m], wv, accSi[m], 0, 0, 0);
        }
        __syncthreads();
    }

    #pragma unroll
    for (int m = 0; m < 2; ++m) {
        int row0 = rowBase + m * 16 + (lane >> 4) * 4;
        int col  = colBase + wave * 16 + fr;
        float bv = bias[col];
        #pragma unroll
        for (int r = 0; r < 4; ++r) {
            float vr = bv - accSi[m][r];
            float vi = bv + accSr[m][r];
            int row = row0 + r;
            size_t idx = (size_t)row * FDIM + col;
            if (O16r_r) {
                O16r_r[idx] = (bf16)vr; O16r_i[idx] = (bf16)vi;
            }
            if (OC) {
                ((unsigned*)OC)[idx] = pack_h2(vr, vi);
            }
        }
    }
}

// ---------------------------------------------------------------------------
// 7. Head via MFMA + fused log_softmax (unchanged).
// ---------------------------------------------------------------------------
__global__ __launch_bounds__(256) void head_mfma(
    const bf16* __restrict__ Yrb,
    const bf16* __restrict__ Yib,
    const bf16* __restrict__ Wcb,
    const float* __restrict__ bc,
    float* __restrict__ out)          // [4096][40]
{
    __shared__ __align__(16) bf16 sY[64][72];
    __shared__ __align__(16) bf16 sW[48][72];
    __shared__ float sS[64][52];

    const int tid  = threadIdx.x;
    const int wave = tid >> 6;
    const int lane = tid & 63;
    const int r0 = blockIdx.x * 64;

    f32x4 acc[3] = {};

    for (int kb = 0; kb < 512; kb += 64) {
        const bf16* src = (kb < 256) ? Yrb : Yib;
        const int koff = kb & 255;
        #pragma unroll
        for (int e = 0; e < 2; ++e) {
            int idx = tid + e * 256;             // 0..511
            int rr = idx >> 3, kk = (idx & 7) * 8;
            *(bf16x8*)&sY[rr][kk] =
                *(const bf16x8*)&src[(size_t)(r0 + rr) * FDIM + koff + kk];
        }
        #pragma unroll
        for (int e = 0; e < 2; ++e) {
            int idx = tid + e * 256;             // need 0..383
            if (idx < 384) {
                int rr = idx >> 3, kk = (idx & 7) * 8;
                *(bf16x8*)&sW[rr][kk] =
                    *(const bf16x8*)&Wcb[(size_t)rr * 512 + kb + kk];
            }
        }
        __syncthreads();
        #pragma unroll
        for (int ks = 0; ks < 2; ++ks) {
            bf16x8 a = *(const bf16x8*)&sY[wave * 16 + (lane & 15)][ks * 32 + (lane >> 4) * 8];
            #pragma unroll
            for (int n = 0; n < 3; ++n) {
                bf16x8 b = *(const bf16x8*)&sW[n * 16 + (lane & 15)][ks * 32 + (lane >> 4) * 8];
                acc[n] = __builtin_amdgcn_mfma_f32_16x16x32_bf16(a, b, acc[n], 0, 0, 0);
            }
        }
        __syncthreads();
    }

    #pragma unroll
    for (int n = 0; n < 3; ++n) {
        int col = n * 16 + (lane & 15);
        int rloc = wave * 16 + (lane >> 4) * 4;
        #pragma unroll
        for (int r = 0; r < 4; ++r)
            sS[rloc + r][col] = acc[n][r];
    }
    __syncthreads();

    if (tid < 64) {
        float mx = -INFINITY;
        #pragma unroll 8
        for (int c = 0; c < CDIM; ++c) {
            float lv = sS[tid][c] + bc[c];
            sS[tid][c] = lv;
            mx = fmaxf(mx, lv);
        }
        float se = 0.f;
        #pragma unroll 8
        for (int c = 0; c < CDIM; ++c) se += expf(sS[tid][c] - mx);
        float lse = mx + logf(se);
        #pragma unroll 8
        for (int c = 0; c < CDIM; ++c)
            out[(size_t)(r0 + tid) * CDIM + c] = sS[tid][c] - lse;
    }
}

// ---------------------------------------------------------------------------
// Launcher
// ---------------------------------------------------------------------------
extern "C" void kernel_launch(void* const* d_in, const int* in_sizes, int n_in,
                              void* d_out, int out_size, void* d_ws, size_t ws_size,
                              hipStream_t stream) {
    const float* real = (const float*)d_in[0];
    const float* imag = (const float*)d_in[1];
    const int*   edges = (const int*)d_in[2];
    const float* q    = (const float*)d_in[3];
    const float* ew   = (const float*)d_in[4];
    const float* W1   = (const float*)d_in[5];
    const float* b1   = (const float*)d_in[6];
    const float* W2   = (const float*)d_in[7];
    const float* b2   = (const float*)d_in[8];
    const float* Wc   = (const float*)d_in[9];
    const float* bc   = (const float*)d_in[10];
    float* out = (float*)d_out;

    // ---- workspace carve-up ----
    char* w = (char*)d_ws;
    int*      hkey   = (int*)w;   w += (size_t)HSIZE * 4;       // 2 MB
    float*    hval   = (float*)w; w += (size_t)HSIZE * 4;       // 2 MB
    int*      cnt    = (int*)w;   w += N_NODES * 4;
    float*    rowsum = (float*)w; w += N_NODES * 4;
    float*    colsum = (float*)w; w += N_NODES * 4;
    size_t zero_bytes = (size_t)((char*)w - (char*)d_ws);
    // Non-zeroed:
    Entry* ent  = (Entry*)w; w += (size_t)N_NODES * CAP * 16;   // 16 MB
    bf16* Xr16 = (bf16*)w; w += NF * 2;
    bf16* Xi16 = (bf16*)w; w += NF * 2;
    f16*  XC   = (f16*)w;  w += NF * 4;                         // interleaved f16
    bf16* Z1r  = (bf16*)w; w += NF * 2;
    bf16* Z1i  = (bf16*)w; w += NF * 2;
    f16*  Z1C  = (f16*)w;  w += NF * 4;
    bf16* Z2r  = (bf16*)w; w += NF * 2;
    bf16* Z2i  = (bf16*)w; w += NF * 2;
    bf16* Y1rb = (bf16*)w; w += NF * 2;
    bf16* Y1ib = (bf16*)w; w += NF * 2;
    f16*  Y1C  = (f16*)w;  w += NF * 4;
    bf16* Y2rb = (bf16*)w; w += NF * 2;
    bf16* Y2ib = (bf16*)w; w += NF * 2;
    bf16* W1t  = (bf16*)w; w += 256 * 768 * 2;
    bf16* W2t  = (bf16*)w; w += 256 * 768 * 2;
    bf16* Wcb  = (bf16*)w; w += 48 * 512 * 2;

    hipMemsetAsync(d_ws, 0, zero_bytes, stream);

    // ---- build sparse L (hash -> ELL) ----
    hash_insert<<<(NEDGE + 255) / 256, 256, 0, stream>>>(edges, ew, hkey, hval,
                                                         rowsum, colsum);
    hash_to_ell<<<HSIZE / 256, 256, 0, stream>>>(hkey, hval, rowsum, colsum,
                                                 q, cnt, ent);

    // ---- merged casts ----
    cast_all<<<(int)(NF / 256) + CAST_W_BLOCKS, 256, 0, stream>>>(
        real, imag, W1, W2, Wc, Xr16, Xi16, XC, W1t, W2t, Wcb);

    dim3 gW(FDIM / 64, N_NODES / 32);   // (4, 128) -> 512 blocks, 2/CU

    // ---- Layer 1 ----
    spmm_k<<<N_NODES, 256, 0, stream>>>(cnt, ent, XC, nullptr,
                                        1.f, 0.f, Z1r, Z1i, Z1C);
    spmm_k<<<N_NODES, 256, 0, stream>>>(cnt, ent, Z1C, XC,
                                        2.f, -1.f, Z2r, Z2i, nullptr);
    wapply_mfma<<<gW, 256, 0, stream>>>(Xr16, Xi16, Z1r, Z1i, Z2r, Z2i,
                                        W1t, b1,
                                        Y1rb, Y1ib,
                                        Y1C);

    // ---- Layer 2 ----
    spmm_k<<<N_NODES, 256, 0, stream>>>(cnt, ent, Y1C, nullptr,
                                        1.f, 0.f, Z1r, Z1i, Z1C);
    spmm_k<<<N_NODES, 256, 0, stream>>>(cnt, ent, Z1C, Y1C,
                                        2.f, -1.f, Z2r, Z2i, nullptr);
    wapply_mfma<<<gW, 256, 0, stream>>>(Y1rb, Y1ib, Z1r, Z1i, Z2r, Z2i,
                                        W2t, b2,
                                        Y2rb, Y2ib,
                                        nullptr);

    // ---- Head ----
    head_mfma<<<64, 256, 0, stream>>>(Y2rb, Y2ib, Wcb, bc, out);
}

// Round 8
// 265.336 us; speedup vs baseline: 1.0382x; 1.0237x over previous
//
#include <hip/hip_runtime.h>
#include <cmath>

#define N_NODES 4096
#define FDIM    256
#define CDIM    40
#define NEDGE   131072
#define CAP     256                  // ELL row capacity (row nnz ~Poisson(64))
#define HBITS   19
#define HSIZE   (1 << HBITS)         // 512K hash slots, load <= 0.25
#define TWO_PI_F 6.28318530717958647692f

typedef __bf16 bf16;
typedef __bf16 bf16x2 __attribute__((ext_vector_type(2)));
typedef __bf16 bf16x4 __attribute__((ext_vector_type(4)));
typedef __bf16 bf16x8 __attribute__((ext_vector_type(8)));
typedef _Float16 f16;
typedef _Float16 f16x2 __attribute__((ext_vector_type(2)));
typedef float  f32x4  __attribute__((ext_vector_type(4)));
typedef unsigned char u8;

static constexpr size_t NF = (size_t)N_NODES * FDIM;      // 1,048,576

// Entry carries PRE-PACKED half2 coefficient pairs:
//   ab = (lr, -li), ba = (li, lr)  so that per complex feature (xr,xi):
//   ar += dot2(ab, x)   ai += dot2(ba, x)   -- one instruction each.
struct __align__(16) Entry { unsigned ab, ba; int col, pad; };

__device__ __forceinline__ unsigned pack_h2(float a, float b) {
    f16x2 h; h[0] = (f16)a; h[1] = (f16)b;
    return __builtin_bit_cast(unsigned, h);
}
__device__ __forceinline__ f16x2 bch2(unsigned u) {
    return __builtin_bit_cast(f16x2, u);
}

// RNE f32 -> fp8 e5m2 (e5m2 == top byte of f16, round-to-nearest-even)
__device__ __forceinline__ unsigned f32_to_e5m2(float v) {
    unsigned short h = __builtin_bit_cast(unsigned short, (f16)v);
    return ((unsigned)h + 0x7Fu + (((unsigned)h >> 8) & 1u)) >> 8 & 0xFFu;
}

// decode 2 packed e5m2 (low 2 bytes of u) -> f16x2 via byte permute:
// result bytes [0, b0, 0, b1]  (e5m2 is the f16 high byte)
__device__ __forceinline__ f16x2 e5m2_pair_lo(unsigned u) {
    return bch2(__builtin_amdgcn_perm(u, 0u, 0x05000400u));
}
// decode bytes 2,3 of u -> f16x2
__device__ __forceinline__ f16x2 e5m2_pair_hi(unsigned u) {
    return bch2(__builtin_amdgcn_perm(u, 0u, 0x07000600u));
}

// 2-way f16 dot product with f32 accumulate: d = a.x*b.x + a.y*b.y + c
__device__ __forceinline__ float fdot2(f16x2 a, f16x2 b, float c) {
#if __has_builtin(__builtin_amdgcn_fdot2)
    return __builtin_amdgcn_fdot2(a, b, c, false);
#else
    asm("v_dot2_f32_f16 %0, %1, %2, %0" : "+v"(c) : "v"(a), "v"(b));
    return c;
#endif
}

// async global->LDS, 16B per lane, dest = ldsBase + lane*16
__device__ __forceinline__ void gld_lds16(const bf16* g, bf16* s) {
    __builtin_amdgcn_global_load_lds(
        (const __attribute__((address_space(1))) void*)g,
        (__attribute__((address_space(3))) void*)s,
        16, 0, 0);
}

__device__ __forceinline__ unsigned cell_hash(unsigned cell) {
    return (cell * 2654435761u) >> (32 - HBITS);
}

// ---------------------------------------------------------------------------
// 1. Hash-insert edges (duplicate weights summed) + raw row/col degree sums.
// ---------------------------------------------------------------------------
__global__ void hash_insert(const int* __restrict__ edges,
                            const float* __restrict__ ew,
                            int* __restrict__ hkey, float* __restrict__ hval,
                            float* __restrict__ rowsum, float* __restrict__ colsum) {
    int e = blockIdx.x * blockDim.x + threadIdx.x;
    if (e >= NEDGE) return;
    int r = edges[e], c = edges[NEDGE + e];
    float wv = ew[e];
    atomicAdd(rowsum + r, wv);
    atomicAdd(colsum + c, wv);
    unsigned cell = (unsigned)r * N_NODES + c;      // < 2^24
    unsigned h = cell_hash(cell);
    for (;;) {
        int old = atomicCAS(hkey + h, 0, (int)(cell + 1));
        if (old == 0 || old == (int)(cell + 1)) { atomicAdd(hval + h, wv); break; }
        h = (h + 1) & (HSIZE - 1);
    }
}

// ---------------------------------------------------------------------------
// 2. Hash -> ELL, dinv inlined; coefficients packed to half2 pairs.
// ---------------------------------------------------------------------------
__global__ __launch_bounds__(256) void hash_to_ell(
    const int* __restrict__ hkey, const float* __restrict__ hval,
    const float* __restrict__ rowsum, const float* __restrict__ colsum,
    const float* __restrict__ qptr,
    int* __restrict__ cnt, Entry* __restrict__ ent) {
    int h = blockIdx.x * 256 + threadIdx.x;
    int k = hkey[h];
    if (k == 0) return;
    unsigned cell = (unsigned)(k - 1);
    int i = cell >> 12, j = cell & 4095;
    float a = hval[h];
    float b = 0.f;
    bool mirror = false;
    if (i == j) { b = a; mirror = true; }
    else {
        unsigned mcell = (unsigned)j * N_NODES + i;
        unsigned hh = cell_hash(mcell);
        for (;;) {
            int kk = hkey[hh];
            if (kk == (int)(mcell + 1)) { b = hval[hh]; mirror = true; break; }
            if (kk == 0) break;
            hh = (hh + 1) & (HSIZE - 1);
        }
    }
    float di = 0.5f * (rowsum[i] + colsum[i]); if (di == 0.f) di = 1.f;
    float dj = 0.5f * (rowsum[j] + colsum[j]); if (dj == 0.f) dj = 1.f;
    float an = 0.5f * (a + b) / sqrtf(di * dj);
    float s, c;
    sincosf(TWO_PI_F * qptr[0] * (a - b), &s, &c);
    float lr = -an * c;
    float li = an * s;                 // for (i,j); conjugate uses -li
    int pos = atomicAdd(cnt + i, 1);
    if (pos < CAP) {
        Entry en; en.ab = pack_h2(lr, -li); en.ba = pack_h2(li, lr);
        en.col = j; en.pad = 0;
        ent[(size_t)i * CAP + pos] = en;
    }
    if (!mirror) {   // emit conjugate cell (j,i): (lr, -li)
        int pos2 = atomicAdd(cnt + j, 1);
        if (pos2 < CAP) {
            Entry en; en.ab = pack_h2(lr, li); en.ba = pack_h2(-li, lr);
            en.col = i; en.pad = 0;
            ent[(size_t)j * CAP + pos2] = en;
        }
    }
}

// ---------------------------------------------------------------------------
// 3. Merged casts: blocks [0,4096) cast X -> planar bf16 + interleaved fp8;
//    remaining blocks cast W1/W2 -> transposed bf16 and Wc -> padded bf16.
// ---------------------------------------------------------------------------
#define NWT (256 * 768)
#define CAST_W_BLOCKS ((2 * NWT + 48 * 512) / 256)   // 1632
__global__ __launch_bounds__(256) void cast_all(
    const float* __restrict__ Xr, const float* __restrict__ Xi,
    const float* __restrict__ W1, const float* __restrict__ W2,
    const float* __restrict__ Wc,
    bf16* __restrict__ Xr16, bf16* __restrict__ Xi16, u8* __restrict__ XC8,
    bf16* __restrict__ W1t, bf16* __restrict__ W2t, bf16* __restrict__ Wcb) {
    int bid = blockIdx.x;
    if (bid < (int)(NF / 256)) {
        int idx = bid * 256 + threadIdx.x;            // n*256+f
        float vr = Xr[idx], vi = Xi[idx];
        Xr16[idx] = (bf16)vr; Xi16[idx] = (bf16)vi;
        unsigned pr = f32_to_e5m2(vr), pi = f32_to_e5m2(vi);
        ((unsigned short*)XC8)[idx] = (unsigned short)(pr | (pi << 8));
    } else {
        int idx = (bid - (int)(NF / 256)) * 256 + threadIdx.x;
        if (idx < 2 * NWT) {
            const float* W = (idx < NWT) ? W1 : W2;
            bf16* Wt = (idx < NWT) ? W1t : W2t;
            int id = (idx < NWT) ? idx : idx - NWT;
            int nout = id / 768, kk = id - nout * 768;
            int o = kk >> 8, k = kk & 255;
            Wt[id] = (bf16)W[((size_t)o * 256 + k) * 256 + nout];
        } else {
            int id = idx - 2 * NWT;
            int row = id >> 9, k = id & 511;
            Wcb[id] = (row < CDIM) ? (bf16)Wc[row * 512 + k] : (bf16)0.f;
        }
    }
}

// ---------------------------------------------------------------------------
// 5. Sparse complex SpMM (ELL), v9: r5 block structure, gathers now fp8 e5m2
//    (8B/lane = 512B/row = 8 cache lines per gather, was 16). Decode via
//    v_perm byte shuffle (e5m2 == f16 high byte); fdot2 MAC core unchanged.
//    Beta/identity term reads PLANAR bf16 (full precision, linear).
// ---------------------------------------------------------------------------
__global__ __launch_bounds__(256) void spmm_k(
    const int* __restrict__ cnt, const Entry* __restrict__ ent,
    const u8* __restrict__ XC8,
    const bf16* __restrict__ C0r, const bf16* __restrict__ C0i,
    float alpha, float beta,
    bf16* __restrict__ Zr, bf16* __restrict__ Zi, u8* __restrict__ ZC8)
{
    __shared__ f32x4 redR[3][64];
    __shared__ f32x4 redI[3][64];

    const int wave = threadIdx.x >> 6, lane = threadIdx.x & 63;
    const int row = blockIdx.x;
    int n1 = cnt[row]; if (n1 > CAP) n1 = CAP;
    const Entry* erow = ent + (size_t)row * CAP;

    float ar[4] = {}, ai[4] = {};
    int e = wave;
    for (; e + 12 < n1; e += 16) {
        Entry e0 = erow[e];
        Entry e1 = erow[e + 4];
        Entry e2 = erow[e + 8];
        Entry e3 = erow[e + 12];
        uint2 x0 = *(const uint2*)&XC8[(size_t)(e0.col & 4095) * 512 + lane * 8];
        uint2 x1 = *(const uint2*)&XC8[(size_t)(e1.col & 4095) * 512 + lane * 8];
        uint2 x2 = *(const uint2*)&XC8[(size_t)(e2.col & 4095) * 512 + lane * 8];
        uint2 x3 = *(const uint2*)&XC8[(size_t)(e3.col & 4095) * 512 + lane * 8];
        {
            f16x2 ab = bch2(e0.ab), ba = bch2(e0.ba);
            f16x2 c0 = e5m2_pair_lo(x0.x), c1 = e5m2_pair_hi(x0.x);
            f16x2 c2 = e5m2_pair_lo(x0.y), c3 = e5m2_pair_hi(x0.y);
            ar[0] = fdot2(ab, c0, ar[0]); ai[0] = fdot2(ba, c0, ai[0]);
            ar[1] = fdot2(ab, c1, ar[1]); ai[1] = fdot2(ba, c1, ai[1]);
            ar[2] = fdot2(ab, c2, ar[2]); ai[2] = fdot2(ba, c2, ai[2]);
            ar[3] = fdot2(ab, c3, ar[3]); ai[3] = fdot2(ba, c3, ai[3]);
        }
        {
            f16x2 ab = bch2(e1.ab), ba = bch2(e1.ba);
            f16x2 c0 = e5m2_pair_lo(x1.x), c1 = e5m2_pair_hi(x1.x);
            f16x2 c2 = e5m2_pair_lo(x1.y), c3 = e5m2_pair_hi(x1.y);
            ar[0] = fdot2(ab, c0, ar[0]); ai[0] = fdot2(ba, c0, ai[0]);
            ar[1] = fdot2(ab, c1, ar[1]); ai[1] = fdot2(ba, c1, ai[1]);
            ar[2] = fdot2(ab, c2, ar[2]); ai[2] = fdot2(ba, c2, ai[2]);
            ar[3] = fdot2(ab, c3, ar[3]); ai[3] = fdot2(ba, c3, ai[3]);
        }
        {
            f16x2 ab = bch2(e2.ab), ba = bch2(e2.ba);
            f16x2 c0 = e5m2_pair_lo(x2.x), c1 = e5m2_pair_hi(x2.x);
            f16x2 c2 = e5m2_pair_lo(x2.y), c3 = e5m2_pair_hi(x2.y);
            ar[0] = fdot2(ab, c0, ar[0]); ai[0] = fdot2(ba, c0, ai[0]);
            ar[1] = fdot2(ab, c1, ar[1]); ai[1] = fdot2(ba, c1, ai[1]);
            ar[2] = fdot2(ab, c2, ar[2]); ai[2] = fdot2(ba, c2, ai[2]);
            ar[3] = fdot2(ab, c3, ar[3]); ai[3] = fdot2(ba, c3, ai[3]);
        }
        {
            f16x2 ab = bch2(e3.ab), ba = bch2(e3.ba);
            f16x2 c0 = e5m2_pair_lo(x3.x), c1 = e5m2_pair_hi(x3.x);
            f16x2 c2 = e5m2_pair_lo(x3.y), c3 = e5m2_pair_hi(x3.y);
            ar[0] = fdot2(ab, c0, ar[0]); ai[0] = fdot2(ba, c0, ai[0]);
            ar[1] = fdot2(ab, c1, ar[1]); ai[1] = fdot2(ba, c1, ai[1]);
            ar[2] = fdot2(ab, c2, ar[2]); ai[2] = fdot2(ba, c2, ai[2]);
            ar[3] = fdot2(ab, c3, ar[3]); ai[3] = fdot2(ba, c3, ai[3]);
        }
    }
    for (; e < n1; e += 4) {
        Entry e0 = erow[e];
        uint2 x0 = *(const uint2*)&XC8[(size_t)(e0.col & 4095) * 512 + lane * 8];
        f16x2 ab = bch2(e0.ab), ba = bch2(e0.ba);
        f16x2 c0 = e5m2_pair_lo(x0.x), c1 = e5m2_pair_hi(x0.x);
        f16x2 c2 = e5m2_pair_lo(x0.y), c3 = e5m2_pair_hi(x0.y);
        ar[0] = fdot2(ab, c0, ar[0]); ai[0] = fdot2(ba, c0, ai[0]);
        ar[1] = fdot2(ab, c1, ar[1]); ai[1] = fdot2(ba, c1, ai[1]);
        ar[2] = fdot2(ab, c2, ar[2]); ai[2] = fdot2(ba, c2, ai[2]);
        ar[3] = fdot2(ab, c3, ar[3]); ai[3] = fdot2(ba, c3, ai[3]);
    }

    if (wave != 0) {
        f32x4 r, i;
        #pragma unroll
        for (int c = 0; c < 4; ++c) { r[c] = ar[c]; i[c] = ai[c]; }
        redR[wave - 1][lane] = r;
        redI[wave - 1][lane] = i;
    }
    __syncthreads();
    if (wave != 0) return;

    #pragma unroll
    for (int w = 0; w < 3; ++w) {
        f32x4 r = redR[w][lane], i = redI[w][lane];
        #pragma unroll
        for (int c = 0; c < 4; ++c) { ar[c] += r[c]; ai[c] += i[c]; }
    }

    size_t pbase = (size_t)row * FDIM + lane * 4;
    float vr[4], vi[4];
    if (beta != 0.f) {
        bf16x4 cr = *(const bf16x4*)&C0r[pbase];
        bf16x4 ci = *(const bf16x4*)&C0i[pbase];
        #pragma unroll
        for (int c = 0; c < 4; ++c) {
            vr[c] = alpha * ar[c] + beta * (float)cr[c];
            vi[c] = alpha * ai[c] + beta * (float)ci[c];
        }
    } else {
        #pragma unroll
        for (int c = 0; c < 4; ++c) { vr[c] = alpha * ar[c]; vi[c] = alpha * ai[c]; }
    }
    bf16x4 pr, pi;
    #pragma unroll
    for (int c = 0; c < 4; ++c) { pr[c] = (bf16)vr[c]; pi[c] = (bf16)vi[c]; }
    *(bf16x4*)&Zr[pbase] = pr;
    *(bf16x4*)&Zi[pbase] = pi;
    if (ZC8) {
        uint2 o;
        o.x = f32_to_e5m2(vr[0]) | (f32_to_e5m2(vi[0]) << 8) |
              (f32_to_e5m2(vr[1]) << 16) | (f32_to_e5m2(vi[1]) << 24);
        o.y = f32_to_e5m2(vr[2]) | (f32_to_e5m2(vi[2]) << 8) |
              (f32_to_e5m2(vr[3]) << 16) | (f32_to_e5m2(vi[3]) << 24);
        *(uint2*)&ZC8[(size_t)row * 512 + lane * 8] = o;
    }
}

// ---------------------------------------------------------------------------
// 6. wapply via MFMA (r7 tiling); interleaved output now fp8 e5m2.
// ---------------------------------------------------------------------------
__global__ __launch_bounds__(256) void wapply_mfma(
    const bf16* __restrict__ Z0r, const bf16* __restrict__ Z0i,
    const bf16* __restrict__ Z1r, const bf16* __restrict__ Z1i,
    const bf16* __restrict__ Z2r, const bf16* __restrict__ Z2i,
    const bf16* __restrict__ Wt,      // [256][768]
    const float* __restrict__ bias,   // [256]
    bf16* __restrict__ O16r_r, bf16* __restrict__ O16r_i,
    u8* __restrict__ OC8)
{
    __shared__ __align__(16) bf16 sZr[32 * 32];
    __shared__ __align__(16) bf16 sZi[32 * 32];
    __shared__ __align__(16) bf16 sW [64 * 32];

    const int tid  = threadIdx.x;
    const int wave = tid >> 6;
    const int lane = tid & 63;
    const int rowBase = blockIdx.y * 32;
    const int colBase = blockIdx.x * 64;

    const int srow = lane >> 2;          // 0..15
    const int skc  = (lane & 3) * 8;

    f32x4 accSr[2] = {}, accSi[2] = {};
    const int fr = lane & 15;
    const int fk = (lane >> 4) * 8;

    for (int kb = 0; kb < 3 * FDIM; kb += 32) {
        int order = kb >> 8;
        int kloc  = kb & 255;
        if (wave == 0 || wave == 1) {
            const bf16* z;
            if (wave == 0) z = (order == 0) ? Z0r : (order == 1) ? Z1r : Z2r;
            else           z = (order == 0) ? Z0i : (order == 1) ? Z1i : Z2i;
            bf16* s = (wave == 0) ? sZr : sZi;
            const bf16* g = z + (size_t)(rowBase + srow) * FDIM + kloc + skc;
            #pragma unroll
            for (int t = 0; t < 2; ++t)
                gld_lds16(g + (size_t)t * 16 * FDIM, s + t * 512);
        } else if (wave == 2) {
            const bf16* g = Wt + (size_t)(colBase + srow) * 768 + kb + skc;
            #pragma unroll
            for (int t = 0; t < 4; ++t)
                gld_lds16(g + (size_t)t * 16 * 768, sW + t * 512);
        }
        __syncthreads();

        bf16x8 zr[2], zi[2], wv;
        #pragma unroll
        for (int m = 0; m < 2; ++m) {
            int r = m * 16 + fr;
            zr[m] = *(const bf16x8*)&sZr[r * 32 + fk];
            zi[m] = *(const bf16x8*)&sZi[r * 32 + fk];
        }
        wv = *(const bf16x8*)&sW[(wave * 16 + fr) * 32 + fk];
        #pragma unroll
        for (int m = 0; m < 2; ++m) {
            accSr[m] = __builtin_amdgcn_mfma_f32_16x16x32_bf16(zr[m], wv, accSr[m], 0, 0, 0);
            accSi[m] = __builtin_amdgcn_mfma_f32_16x16x32_bf16(zi[m], wv, accSi[m], 0, 0, 0);
        }
        __syncthreads();
    }

    #pragma unroll
    for (int m = 0; m < 2; ++m) {
        int row0 = rowBase + m * 16 + (lane >> 4) * 4;
        int col  = colBase + wave * 16 + fr;
        float bv = bias[col];
        #pragma unroll
        for (int r = 0; r < 4; ++r) {
            float vr = bv - accSi[m][r];
            float vi = bv + accSr[m][r];
            int row = row0 + r;
            size_t idx = (size_t)row * FDIM + col;
            if (O16r_r) {
                O16r_r[idx] = (bf16)vr; O16r_i[idx] = (bf16)vi;
            }
            if (OC8) {
                unsigned pr = f32_to_e5m2(vr), pi = f32_to_e5m2(vi);
                ((unsigned short*)OC8)[idx] = (unsigned short)(pr | (pi << 8));
            }
        }
    }
}

// ---------------------------------------------------------------------------
// 7. Head via MFMA + fused log_softmax (unchanged).
// ---------------------------------------------------------------------------
__global__ __launch_bounds__(256) void head_mfma(
    const bf16* __restrict__ Yrb,
    const bf16* __restrict__ Yib,
    const bf16* __restrict__ Wcb,
    const float* __restrict__ bc,
    float* __restrict__ out)          // [4096][40]
{
    __shared__ __align__(16) bf16 sY[64][72];
    __shared__ __align__(16) bf16 sW[48][72];
    __shared__ float sS[64][52];

    const int tid  = threadIdx.x;
    const int wave = tid >> 6;
    const int lane = tid & 63;
    const int r0 = blockIdx.x * 64;

    f32x4 acc[3] = {};

    for (int kb = 0; kb < 512; kb += 64) {
        const bf16* src = (kb < 256) ? Yrb : Yib;
        const int koff = kb & 255;
        #pragma unroll
        for (int e = 0; e < 2; ++e) {
            int idx = tid + e * 256;             // 0..511
            int rr = idx >> 3, kk = (idx & 7) * 8;
            *(bf16x8*)&sY[rr][kk] =
                *(const bf16x8*)&src[(size_t)(r0 + rr) * FDIM + koff + kk];
        }
        #pragma unroll
        for (int e = 0; e < 2; ++e) {
            int idx = tid + e * 256;             // need 0..383
            if (idx < 384) {
                int rr = idx >> 3, kk = (idx & 7) * 8;
                *(bf16x8*)&sW[rr][kk] =
                    *(const bf16x8*)&Wcb[(size_t)rr * 512 + kb + kk];
            }
        }
        __syncthreads();
        #pragma unroll
        for (int ks = 0; ks < 2; ++ks) {
            bf16x8 a = *(const bf16x8*)&sY[wave * 16 + (lane & 15)][ks * 32 + (lane >> 4) * 8];
            #pragma unroll
            for (int n = 0; n < 3; ++n) {
                bf16x8 b = *(const bf16x8*)&sW[n * 16 + (lane & 15)][ks * 32 + (lane >> 4) * 8];
                acc[n] = __builtin_amdgcn_mfma_f32_16x16x32_bf16(a, b, acc[n], 0, 0, 0);
            }
        }
        __syncthreads();
    }

    #pragma unroll
    for (int n = 0; n < 3; ++n) {
        int col = n * 16 + (lane & 15);
        int rloc = wave * 16 + (lane >> 4) * 4;
        #pragma unroll
        for (int r = 0; r < 4; ++r)
            sS[rloc + r][col] = acc[n][r];
    }
    __syncthreads();

    if (tid < 64) {
        float mx = -INFINITY;
        #pragma unroll 8
        for (int c = 0; c < CDIM; ++c) {
            float lv = sS[tid][c] + bc[c];
            sS[tid][c] = lv;
            mx = fmaxf(mx, lv);
        }
        float se = 0.f;
        #pragma unroll 8
        for (int c = 0; c < CDIM; ++c) se += expf(sS[tid][c] - mx);
        float lse = mx + logf(se);
        #pragma unroll 8
        for (int c = 0; c < CDIM; ++c)
            out[(size_t)(r0 + tid) * CDIM + c] = sS[tid][c] - lse;
    }
}

// ---------------------------------------------------------------------------
// Launcher
// ---------------------------------------------------------------------------
extern "C" void kernel_launch(void* const* d_in, const int* in_sizes, int n_in,
                              void* d_out, int out_size, void* d_ws, size_t ws_size,
                              hipStream_t stream) {
    const float* real = (const float*)d_in[0];
    const float* imag = (const float*)d_in[1];
    const int*   edges = (const int*)d_in[2];
    const float* q    = (const float*)d_in[3];
    const float* ew   = (const float*)d_in[4];
    const float* W1   = (const float*)d_in[5];
    const float* b1   = (const float*)d_in[6];
    const float* W2   = (const float*)d_in[7];
    const float* b2   = (const float*)d_in[8];
    const float* Wc   = (const float*)d_in[9];
    const float* bc   = (const float*)d_in[10];
    float* out = (float*)d_out;

    // ---- workspace carve-up ----
    char* w = (char*)d_ws;
    int*      hkey   = (int*)w;   w += (size_t)HSIZE * 4;       // 2 MB
    float*    hval   = (float*)w; w += (size_t)HSIZE * 4;       // 2 MB
    int*      cnt    = (int*)w;   w += N_NODES * 4;
    float*    rowsum = (float*)w; w += N_NODES * 4;
    float*    colsum = (float*)w; w += N_NODES * 4;
    size_t zero_bytes = (size_t)((char*)w - (char*)d_ws);
    // Non-zeroed:
    Entry* ent  = (Entry*)w; w += (size_t)N_NODES * CAP * 16;   // 16 MB
    bf16* Xr16 = (bf16*)w; w += NF * 2;
    bf16* Xi16 = (bf16*)w; w += NF * 2;
    u8*   XC8  = (u8*)w;   w += NF * 2;                         // interleaved fp8
    bf16* Z1r  = (bf16*)w; w += NF * 2;
    bf16* Z1i  = (bf16*)w; w += NF * 2;
    u8*   Z1C8 = (u8*)w;   w += NF * 2;
    bf16* Z2r  = (bf16*)w; w += NF * 2;
    bf16* Z2i  = (bf16*)w; w += NF * 2;
    bf16* Y1rb = (bf16*)w; w += NF * 2;
    bf16* Y1ib = (bf16*)w; w += NF * 2;
    u8*   Y1C8 = (u8*)w;   w += NF * 2;
    bf16* Y2rb = (bf16*)w; w += NF * 2;
    bf16* Y2ib = (bf16*)w; w += NF * 2;
    bf16* W1t  = (bf16*)w; w += 256 * 768 * 2;
    bf16* W2t  = (bf16*)w; w += 256 * 768 * 2;
    bf16* Wcb  = (bf16*)w; w += 48 * 512 * 2;

    hipMemsetAsync(d_ws, 0, zero_bytes, stream);

    // ---- build sparse L (hash -> ELL) ----
    hash_insert<<<(NEDGE + 255) / 256, 256, 0, stream>>>(edges, ew, hkey, hval,
                                                         rowsum, colsum);
    hash_to_ell<<<HSIZE / 256, 256, 0, stream>>>(hkey, hval, rowsum, colsum,
                                                 q, cnt, ent);

    // ---- merged casts ----
    cast_all<<<(int)(NF / 256) + CAST_W_BLOCKS, 256, 0, stream>>>(
        real, imag, W1, W2, Wc, Xr16, Xi16, XC8, W1t, W2t, Wcb);

    dim3 gW(FDIM / 64, N_NODES / 32);   // (4, 128) -> 512 blocks, 2/CU

    // ---- Layer 1 ----
    spmm_k<<<N_NODES, 256, 0, stream>>>(cnt, ent, XC8, nullptr, nullptr,
                                        1.f, 0.f, Z1r, Z1i, Z1C8);
    spmm_k<<<N_NODES, 256, 0, stream>>>(cnt, ent, Z1C8, Xr16, Xi16,
                                        2.f, -1.f, Z2r, Z2i, nullptr);
    wapply_mfma<<<gW, 256, 0, stream>>>(Xr16, Xi16, Z1r, Z1i, Z2r, Z2i,
                                        W1t, b1,
                                        Y1rb, Y1ib,
                                        Y1C8);

    // ---- Layer 2 ----
    spmm_k<<<N_NODES, 256, 0, stream>>>(cnt, ent, Y1C8, nullptr, nullptr,
                                        1.f, 0.f, Z1r, Z1i, Z1C8);
    spmm_k<<<N_NODES, 256, 0, stream>>>(cnt, ent, Z1C8, Y1rb, Y1ib,
                                        2.f, -1.f, Z2r, Z2i, nullptr);
    wapply_mfma<<<gW, 256, 0, stream>>>(Y1rb, Y1ib, Z1r, Z1i, Z2r, Z2i,
                                        W2t, b2,
                                        Y2rb, Y2ib,
                                        nullptr);

    // ---- Head ----
    head_mfma<<<64, 256, 0, stream>>>(Y2rb, Y2ib, Wcb, bc, out);
}

// Round 9
// 236.584 us; speedup vs baseline: 1.1644x; 1.1215x over previous
//
#include <hip/hip_runtime.h>
#include <cmath>

#define N_NODES 4096
#define FDIM    256
#define CDIM    40
#define NEDGE   131072
#define CAP     256                  // ELL row capacity (row nnz ~Poisson(64))
#define HBITS   19
#define HSIZE   (1 << HBITS)         // 512K hash slots, load <= 0.25
#define TWO_PI_F 6.28318530717958647692f

typedef __bf16 bf16;
typedef __bf16 bf16x2 __attribute__((ext_vector_type(2)));
typedef __bf16 bf16x4 __attribute__((ext_vector_type(4)));
typedef __bf16 bf16x8 __attribute__((ext_vector_type(8)));
typedef _Float16 f16;
typedef _Float16 f16x2 __attribute__((ext_vector_type(2)));
typedef float  f32x4  __attribute__((ext_vector_type(4)));
typedef unsigned char u8;

static constexpr size_t NF = (size_t)N_NODES * FDIM;      // 1,048,576

// Entry carries PRE-PACKED half2 coefficient pairs:
//   ab = (lr, -li), ba = (li, lr)  so that per complex feature (xr,xi):
//   ar += dot2(ab, x)   ai += dot2(ba, x)   -- one instruction each.
struct __align__(16) Entry { unsigned ab, ba; int col, pad; };

__device__ __forceinline__ unsigned pack_h2(float a, float b) {
    f16x2 h; h[0] = (f16)a; h[1] = (f16)b;
    return __builtin_bit_cast(unsigned, h);
}
__device__ __forceinline__ f16x2 bch2(unsigned u) {
    return __builtin_bit_cast(f16x2, u);
}

// RNE f32 -> fp8 e5m2 (e5m2 == top byte of f16, round-to-nearest-even)
__device__ __forceinline__ unsigned f32_to_e5m2(float v) {
    unsigned short h = __builtin_bit_cast(unsigned short, (f16)v);
    return ((unsigned)h + 0x7Fu + (((unsigned)h >> 8) & 1u)) >> 8 & 0xFFu;
}

// decode 2 packed e5m2 (low 2 bytes of u) -> f16x2 via byte permute
__device__ __forceinline__ f16x2 e5m2_pair_lo(unsigned u) {
    return bch2(__builtin_amdgcn_perm(u, 0u, 0x05000400u));
}
__device__ __forceinline__ f16x2 e5m2_pair_hi(unsigned u) {
    return bch2(__builtin_amdgcn_perm(u, 0u, 0x07000600u));
}

// 2-way f16 dot product with f32 accumulate: d = a.x*b.x + a.y*b.y + c
__device__ __forceinline__ float fdot2(f16x2 a, f16x2 b, float c) {
#if __has_builtin(__builtin_amdgcn_fdot2)
    return __builtin_amdgcn_fdot2(a, b, c, false);
#else
    asm("v_dot2_f32_f16 %0, %1, %2, %0" : "+v"(c) : "v"(a), "v"(b));
    return c;
#endif
}

// async global->LDS, 16B per lane: src = per-lane gaddr, dest = uniform base
// (HW adds lane*16 to the LDS base)
__device__ __forceinline__ void gld_lds16(const void* g, void* s) {
    __builtin_amdgcn_global_load_lds(
        (const __attribute__((address_space(1))) void*)g,
        (__attribute__((address_space(3))) void*)s,
        16, 0, 0);
}

__device__ __forceinline__ unsigned cell_hash(unsigned cell) {
    return (cell * 2654435761u) >> (32 - HBITS);
}

// ---------------------------------------------------------------------------
// 1. Fused prep: blocks [0,512) hash-insert edges (+row/col sums);
//    blocks [512, 512+4096) cast X -> planar bf16 + interleaved fp8;
//    remaining blocks cast W1/W2 -> transposed bf16 and Wc -> padded bf16.
// ---------------------------------------------------------------------------
#define NWT (256 * 768)
#define HASH_BLOCKS ((NEDGE + 255) / 256)            // 512
#define XCAST_BLOCKS ((int)(NF / 256))               // 4096
#define WCAST_BLOCKS ((2 * NWT + 48 * 512) / 256)    // 1632
__global__ __launch_bounds__(256) void prep_k(
    const int* __restrict__ edges, const float* __restrict__ ew,
    int* __restrict__ hkey, float* __restrict__ hval,
    float* __restrict__ rowsum, float* __restrict__ colsum,
    const float* __restrict__ Xr, const float* __restrict__ Xi,
    const float* __restrict__ W1, const float* __restrict__ W2,
    const float* __restrict__ Wc,
    bf16* __restrict__ Xr16, bf16* __restrict__ Xi16, u8* __restrict__ XC8,
    bf16* __restrict__ W1t, bf16* __restrict__ W2t, bf16* __restrict__ Wcb) {
    int bid = blockIdx.x;
    if (bid < HASH_BLOCKS) {
        int e = bid * 256 + threadIdx.x;
        if (e >= NEDGE) return;
        int r = edges[e], c = edges[NEDGE + e];
        float wv = ew[e];
        atomicAdd(rowsum + r, wv);
        atomicAdd(colsum + c, wv);
        unsigned cell = (unsigned)r * N_NODES + c;      // < 2^24
        unsigned h = cell_hash(cell);
        for (;;) {
            int old = atomicCAS(hkey + h, 0, (int)(cell + 1));
            if (old == 0 || old == (int)(cell + 1)) { atomicAdd(hval + h, wv); break; }
            h = (h + 1) & (HSIZE - 1);
        }
    } else if (bid < HASH_BLOCKS + XCAST_BLOCKS) {
        int idx = (bid - HASH_BLOCKS) * 256 + threadIdx.x;   // n*256+f
        float vr = Xr[idx], vi = Xi[idx];
        Xr16[idx] = (bf16)vr; Xi16[idx] = (bf16)vi;
        unsigned pr = f32_to_e5m2(vr), pi = f32_to_e5m2(vi);
        ((unsigned short*)XC8)[idx] = (unsigned short)(pr | (pi << 8));
    } else {
        int idx = (bid - HASH_BLOCKS - XCAST_BLOCKS) * 256 + threadIdx.x;
        if (idx < 2 * NWT) {
            const float* W = (idx < NWT) ? W1 : W2;
            bf16* Wt = (idx < NWT) ? W1t : W2t;
            int id = (idx < NWT) ? idx : idx - NWT;
            int nout = id / 768, kk = id - nout * 768;
            int o = kk >> 8, k = kk & 255;
            Wt[id] = (bf16)W[((size_t)o * 256 + k) * 256 + nout];
        } else {
            int id = idx - 2 * NWT;
            int row = id >> 9, k = id & 511;
            Wcb[id] = (row < CDIM) ? (bf16)Wc[row * 512 + k] : (bf16)0.f;
        }
    }
}

// ---------------------------------------------------------------------------
// 2. Hash -> ELL, dinv inlined; coefficients packed to half2 pairs.
// ---------------------------------------------------------------------------
__global__ __launch_bounds__(256) void hash_to_ell(
    const int* __restrict__ hkey, const float* __restrict__ hval,
    const float* __restrict__ rowsum, const float* __restrict__ colsum,
    const float* __restrict__ qptr,
    int* __restrict__ cnt, Entry* __restrict__ ent) {
    int h = blockIdx.x * 256 + threadIdx.x;
    int k = hkey[h];
    if (k == 0) return;
    unsigned cell = (unsigned)(k - 1);
    int i = cell >> 12, j = cell & 4095;
    float a = hval[h];
    float b = 0.f;
    bool mirror = false;
    if (i == j) { b = a; mirror = true; }
    else {
        unsigned mcell = (unsigned)j * N_NODES + i;
        unsigned hh = cell_hash(mcell);
        for (;;) {
            int kk = hkey[hh];
            if (kk == (int)(mcell + 1)) { b = hval[hh]; mirror = true; break; }
            if (kk == 0) break;
            hh = (hh + 1) & (HSIZE - 1);
        }
    }
    float di = 0.5f * (rowsum[i] + colsum[i]); if (di == 0.f) di = 1.f;
    float dj = 0.5f * (rowsum[j] + colsum[j]); if (dj == 0.f) dj = 1.f;
    float an = 0.5f * (a + b) / sqrtf(di * dj);
    float s, c;
    sincosf(TWO_PI_F * qptr[0] * (a - b), &s, &c);
    float lr = -an * c;
    float li = an * s;                 // for (i,j); conjugate uses -li
    int pos = atomicAdd(cnt + i, 1);
    if (pos < CAP) {
        Entry en; en.ab = pack_h2(lr, -li); en.ba = pack_h2(li, lr);
        en.col = j; en.pad = 0;
        ent[(size_t)i * CAP + pos] = en;
    }
    if (!mirror) {   // emit conjugate cell (j,i): (lr, -li)
        int pos2 = atomicAdd(cnt + j, 1);
        if (pos2 < CAP) {
            Entry en; en.ab = pack_h2(lr, li); en.ba = pack_h2(-li, lr);
            en.col = i; en.pad = 0;
            ent[(size_t)j * CAP + pos2] = en;
        }
    }
}

// ---------------------------------------------------------------------------
// 3. Sparse complex SpMM (ELL), v10: ENTRIES STAGED IN LDS.
//    One gld_lds16 per 64 entries (lane i -> sent[i]) removes the HBM
//    entry-load from the gather dependency chain. After one barrier, each
//    wave reads entries via ds_read_b128 and issues 8 gathers back-to-back.
// ---------------------------------------------------------------------------
__global__ __launch_bounds__(256) void spmm_k(
    const int* __restrict__ cnt, const Entry* __restrict__ ent,
    const u8* __restrict__ XC8,
    const bf16* __restrict__ C0r, const bf16* __restrict__ C0i,
    float alpha, float beta,
    bf16* __restrict__ Zr, bf16* __restrict__ Zi, u8* __restrict__ ZC8)
{
    __shared__ __align__(16) Entry sent[CAP];        // 4 KB
    __shared__ f32x4 redR[3][64];
    __shared__ f32x4 redI[3][64];

    const int wave = threadIdx.x >> 6, lane = threadIdx.x & 63;
    const int row = blockIdx.x;
    int n1 = cnt[row]; if (n1 > CAP) n1 = CAP;
    const Entry* erow = ent + (size_t)row * CAP;

    // stage this row's entries: wave w stages entries [w*64, w*64+64)
    if (wave * 64 < n1)
        gld_lds16(erow + wave * 64 + lane, sent + wave * 64);
    __syncthreads();                                 // drains vmcnt+lgkmcnt

    float ar[4] = {}, ai[4] = {};
    int e = wave;
    // 8 gathers in flight; entries from LDS (no HBM in the chain)
    for (; e + 28 < n1; e += 32) {
        Entry ee[8];
        #pragma unroll
        for (int u = 0; u < 8; ++u)
            ee[u] = sent[e + 4 * u];
        uint2 xv[8];
        #pragma unroll
        for (int u = 0; u < 8; ++u)
            xv[u] = *(const uint2*)&XC8[(size_t)(ee[u].col & 4095) * 512 + lane * 8];
        #pragma unroll
        for (int u = 0; u < 8; ++u) {
            f16x2 ab = bch2(ee[u].ab), ba = bch2(ee[u].ba);
            f16x2 c0 = e5m2_pair_lo(xv[u].x), c1 = e5m2_pair_hi(xv[u].x);
            f16x2 c2 = e5m2_pair_lo(xv[u].y), c3 = e5m2_pair_hi(xv[u].y);
            ar[0] = fdot2(ab, c0, ar[0]); ai[0] = fdot2(ba, c0, ai[0]);
            ar[1] = fdot2(ab, c1, ar[1]); ai[1] = fdot2(ba, c1, ai[1]);
            ar[2] = fdot2(ab, c2, ar[2]); ai[2] = fdot2(ba, c2, ai[2]);
            ar[3] = fdot2(ab, c3, ar[3]); ai[3] = fdot2(ba, c3, ai[3]);
        }
    }
    for (; e < n1; e += 4) {
        Entry e0 = sent[e];
        uint2 x0 = *(const uint2*)&XC8[(size_t)(e0.col & 4095) * 512 + lane * 8];
        f16x2 ab = bch2(e0.ab), ba = bch2(e0.ba);
        f16x2 c0 = e5m2_pair_lo(x0.x), c1 = e5m2_pair_hi(x0.x);
        f16x2 c2 = e5m2_pair_lo(x0.y), c3 = e5m2_pair_hi(x0.y);
        ar[0] = fdot2(ab, c0, ar[0]); ai[0] = fdot2(ba, c0, ai[0]);
        ar[1] = fdot2(ab, c1, ar[1]); ai[1] = fdot2(ba, c1, ai[1]);
        ar[2] = fdot2(ab, c2, ar[2]); ai[2] = fdot2(ba, c2, ai[2]);
        ar[3] = fdot2(ab, c3, ar[3]); ai[3] = fdot2(ba, c3, ai[3]);
    }

    if (wave != 0) {
        f32x4 r, i;
        #pragma unroll
        for (int c = 0; c < 4; ++c) { r[c] = ar[c]; i[c] = ai[c]; }
        redR[wave - 1][lane] = r;
        redI[wave - 1][lane] = i;
    }
    __syncthreads();
    if (wave != 0) return;

    #pragma unroll
    for (int w = 0; w < 3; ++w) {
        f32x4 r = redR[w][lane], i = redI[w][lane];
        #pragma unroll
        for (int c = 0; c < 4; ++c) { ar[c] += r[c]; ai[c] += i[c]; }
    }

    size_t pbase = (size_t)row * FDIM + lane * 4;
    float vr[4], vi[4];
    if (beta != 0.f) {
        bf16x4 cr = *(const bf16x4*)&C0r[pbase];
        bf16x4 ci = *(const bf16x4*)&C0i[pbase];
        #pragma unroll
        for (int c = 0; c < 4; ++c) {
            vr[c] = alpha * ar[c] + beta * (float)cr[c];
            vi[c] = alpha * ai[c] + beta * (float)ci[c];
        }
    } else {
        #pragma unroll
        for (int c = 0; c < 4; ++c) { vr[c] = alpha * ar[c]; vi[c] = alpha * ai[c]; }
    }
    bf16x4 pr, pi;
    #pragma unroll
    for (int c = 0; c < 4; ++c) { pr[c] = (bf16)vr[c]; pi[c] = (bf16)vi[c]; }
    *(bf16x4*)&Zr[pbase] = pr;
    *(bf16x4*)&Zi[pbase] = pi;
    if (ZC8) {
        uint2 o;
        o.x = f32_to_e5m2(vr[0]) | (f32_to_e5m2(vi[0]) << 8) |
              (f32_to_e5m2(vr[1]) << 16) | (f32_to_e5m2(vi[1]) << 24);
        o.y = f32_to_e5m2(vr[2]) | (f32_to_e5m2(vi[2]) << 8) |
              (f32_to_e5m2(vr[3]) << 16) | (f32_to_e5m2(vi[3]) << 24);
        *(uint2*)&ZC8[(size_t)row * 512 + lane * 8] = o;
    }
}

// ---------------------------------------------------------------------------
// 4. wapply via MFMA (r8 version, unchanged).
// ---------------------------------------------------------------------------
__global__ __launch_bounds__(256) void wapply_mfma(
    const bf16* __restrict__ Z0r, const bf16* __restrict__ Z0i,
    const bf16* __restrict__ Z1r, const bf16* __restrict__ Z1i,
    const bf16* __restrict__ Z2r, const bf16* __restrict__ Z2i,
    const bf16* __restrict__ Wt,      // [256][768]
    const float* __restrict__ bias,   // [256]
    bf16* __restrict__ O16r_r, bf16* __restrict__ O16r_i,
    u8* __restrict__ OC8)
{
    __shared__ __align__(16) bf16 sZr[32 * 32];
    __shared__ __align__(16) bf16 sZi[32 * 32];
    __shared__ __align__(16) bf16 sW [64 * 32];

    const int tid  = threadIdx.x;
    const int wave = tid >> 6;
    const int lane = tid & 63;
    const int rowBase = blockIdx.y * 32;
    const int colBase = blockIdx.x * 64;

    const int srow = lane >> 2;          // 0..15
    const int skc  = (lane & 3) * 8;

    f32x4 accSr[2] = {}, accSi[2] = {};
    const int fr = lane & 15;
    const int fk = (lane >> 4) * 8;

    for (int kb = 0; kb < 3 * FDIM; kb += 32) {
        int order = kb >> 8;
        int kloc  = kb & 255;
        if (wave == 0 || wave == 1) {
            const bf16* z;
            if (wave == 0) z = (order == 0) ? Z0r : (order == 1) ? Z1r : Z2r;
            else           z = (order == 0) ? Z0i : (order == 1) ? Z1i : Z2i;
            bf16* s = (wave == 0) ? sZr : sZi;
            const bf16* g = z + (size_t)(rowBase + srow) * FDIM + kloc + skc;
            #pragma unroll
            for (int t = 0; t < 2; ++t)
                gld_lds16(g + (size_t)t * 16 * FDIM, s + t * 512);
        } else if (wave == 2) {
            const bf16* g = Wt + (size_t)(colBase + srow) * 768 + kb + skc;
            #pragma unroll
            for (int t = 0; t < 4; ++t)
                gld_lds16(g + (size_t)t * 16 * 768, sW + t * 512);
        }
        __syncthreads();

        bf16x8 zr[2], zi[2], wv;
        #pragma unroll
        for (int m = 0; m < 2; ++m) {
            int r = m * 16 + fr;
            zr[m] = *(const bf16x8*)&sZr[r * 32 + fk];
            zi[m] = *(const bf16x8*)&sZi[r * 32 + fk];
        }
        wv = *(const bf16x8*)&sW[(wave * 16 + fr) * 32 + fk];
        #pragma unroll
        for (int m = 0; m < 2; ++m) {
            accSr[m] = __builtin_amdgcn_mfma_f32_16x16x32_bf16(zr[m], wv, accSr[m], 0, 0, 0);
            accSi[m] = __builtin_amdgcn_mfma_f32_16x16x32_bf16(zi[m], wv, accSi[m], 0, 0, 0);
        }
        __syncthreads();
    }

    #pragma unroll
    for (int m = 0; m < 2; ++m) {
        int row0 = rowBase + m * 16 + (lane >> 4) * 4;
        int col  = colBase + wave * 16 + fr;
        float bv = bias[col];
        #pragma unroll
        for (int r = 0; r < 4; ++r) {
            float vr = bv - accSi[m][r];
            float vi = bv + accSr[m][r];
            int row = row0 + r;
            size_t idx = (size_t)row * FDIM + col;
            if (O16r_r) {
                O16r_r[idx] = (bf16)vr; O16r_i[idx] = (bf16)vi;
            }
            if (OC8) {
                unsigned pr = f32_to_e5m2(vr), pi = f32_to_e5m2(vi);
                ((unsigned short*)OC8)[idx] = (unsigned short)(pr | (pi << 8));
            }
        }
    }
}

// ---------------------------------------------------------------------------
// 5. Head via MFMA + fused log_softmax (unchanged).
// ---------------------------------------------------------------------------
__global__ __launch_bounds__(256) void head_mfma(
    const bf16* __restrict__ Yrb,
    const bf16* __restrict__ Yib,
    const bf16* __restrict__ Wcb,
    const float* __restrict__ bc,
    float* __restrict__ out)          // [4096][40]
{
    __shared__ __align__(16) bf16 sY[64][72];
    __shared__ __align__(16) bf16 sW[48][72];
    __shared__ float sS[64][52];

    const int tid  = threadIdx.x;
    const int wave = tid >> 6;
    const int lane = tid & 63;
    const int r0 = blockIdx.x * 64;

    f32x4 acc[3] = {};

    for (int kb = 0; kb < 512; kb += 64) {
        const bf16* src = (kb < 256) ? Yrb : Yib;
        const int koff = kb & 255;
        #pragma unroll
        for (int e = 0; e < 2; ++e) {
            int idx = tid + e * 256;             // 0..511
            int rr = idx >> 3, kk = (idx & 7) * 8;
            *(bf16x8*)&sY[rr][kk] =
                *(const bf16x8*)&src[(size_t)(r0 + rr) * FDIM + koff + kk];
        }
        #pragma unroll
        for (int e = 0; e < 2; ++e) {
            int idx = tid + e * 256;             // need 0..383
            if (idx < 384) {
                int rr = idx >> 3, kk = (idx & 7) * 8;
                *(bf16x8*)&sW[rr][kk] =
                    *(const bf16x8*)&Wcb[(size_t)rr * 512 + kb + kk];
            }
        }
        __syncthreads();
        #pragma unroll
        for (int ks = 0; ks < 2; ++ks) {
            bf16x8 a = *(const bf16x8*)&sY[wave * 16 + (lane & 15)][ks * 32 + (lane >> 4) * 8];
            #pragma unroll
            for (int n = 0; n < 3; ++n) {
                bf16x8 b = *(const bf16x8*)&sW[n * 16 + (lane & 15)][ks * 32 + (lane >> 4) * 8];
                acc[n] = __builtin_amdgcn_mfma_f32_16x16x32_bf16(a, b, acc[n], 0, 0, 0);
            }
        }
        __syncthreads();
    }

    #pragma unroll
    for (int n = 0; n < 3; ++n) {
        int col = n * 16 + (lane & 15);
        int rloc = wave * 16 + (lane >> 4) * 4;
        #pragma unroll
        for (int r = 0; r < 4; ++r)
            sS[rloc + r][col] = acc[n][r];
    }
    __syncthreads();

    if (tid < 64) {
        float mx = -INFINITY;
        #pragma unroll 8
        for (int c = 0; c < CDIM; ++c) {
            float lv = sS[tid][c] + bc[c];
            sS[tid][c] = lv;
            mx = fmaxf(mx, lv);
        }
        float se = 0.f;
        #pragma unroll 8
        for (int c = 0; c < CDIM; ++c) se += expf(sS[tid][c] - mx);
        float lse = mx + logf(se);
        #pragma unroll 8
        for (int c = 0; c < CDIM; ++c)
            out[(size_t)(r0 + tid) * CDIM + c] = sS[tid][c] - lse;
    }
}

// ---------------------------------------------------------------------------
// Launcher
// ---------------------------------------------------------------------------
extern "C" void kernel_launch(void* const* d_in, const int* in_sizes, int n_in,
                              void* d_out, int out_size, void* d_ws, size_t ws_size,
                              hipStream_t stream) {
    const float* real = (const float*)d_in[0];
    const float* imag = (const float*)d_in[1];
    const int*   edges = (const int*)d_in[2];
    const float* q    = (const float*)d_in[3];
    const float* ew   = (const float*)d_in[4];
    const float* W1   = (const float*)d_in[5];
    const float* b1   = (const float*)d_in[6];
    const float* W2   = (const float*)d_in[7];
    const float* b2   = (const float*)d_in[8];
    const float* Wc   = (const float*)d_in[9];
    const float* bc   = (const float*)d_in[10];
    float* out = (float*)d_out;

    // ---- workspace carve-up ----
    char* w = (char*)d_ws;
    int*      hkey   = (int*)w;   w += (size_t)HSIZE * 4;       // 2 MB
    float*    hval   = (float*)w; w += (size_t)HSIZE * 4;       // 2 MB
    int*      cnt    = (int*)w;   w += N_NODES * 4;
    float*    rowsum = (float*)w; w += N_NODES * 4;
    float*    colsum = (float*)w; w += N_NODES * 4;
    size_t zero_bytes = (size_t)((char*)w - (char*)d_ws);
    // Non-zeroed:
    Entry* ent  = (Entry*)w; w += (size_t)N_NODES * CAP * 16;   // 16 MB
    bf16* Xr16 = (bf16*)w; w += NF * 2;
    bf16* Xi16 = (bf16*)w; w += NF * 2;
    u8*   XC8  = (u8*)w;   w += NF * 2;                         // interleaved fp8
    bf16* Z1r  = (bf16*)w; w += NF * 2;
    bf16* Z1i  = (bf16*)w; w += NF * 2;
    u8*   Z1C8 = (u8*)w;   w += NF * 2;
    bf16* Z2r  = (bf16*)w; w += NF * 2;
    bf16* Z2i  = (bf16*)w; w += NF * 2;
    bf16* Y1rb = (bf16*)w; w += NF * 2;
    bf16* Y1ib = (bf16*)w; w += NF * 2;
    u8*   Y1C8 = (u8*)w;   w += NF * 2;
    bf16* Y2rb = (bf16*)w; w += NF * 2;
    bf16* Y2ib = (bf16*)w; w += NF * 2;
    bf16* W1t  = (bf16*)w; w += 256 * 768 * 2;
    bf16* W2t  = (bf16*)w; w += 256 * 768 * 2;
    bf16* Wcb  = (bf16*)w; w += 48 * 512 * 2;

    hipMemsetAsync(d_ws, 0, zero_bytes, stream);

    // ---- fused prep (hash insert + all casts) ----
    prep_k<<<HASH_BLOCKS + XCAST_BLOCKS + WCAST_BLOCKS, 256, 0, stream>>>(
        edges, ew, hkey, hval, rowsum, colsum,
        real, imag, W1, W2, Wc,
        Xr16, Xi16, XC8, W1t, W2t, Wcb);

    hash_to_ell<<<HSIZE / 256, 256, 0, stream>>>(hkey, hval, rowsum, colsum,
                                                 q, cnt, ent);

    dim3 gW(FDIM / 64, N_NODES / 32);   // (4, 128) -> 512 blocks, 2/CU

    // ---- Layer 1 ----
    spmm_k<<<N_NODES, 256, 0, stream>>>(cnt, ent, XC8, nullptr, nullptr,
                                        1.f, 0.f, Z1r, Z1i, Z1C8);
    spmm_k<<<N_NODES, 256, 0, stream>>>(cnt, ent, Z1C8, Xr16, Xi16,
                                        2.f, -1.f, Z2r, Z2i, nullptr);
    wapply_mfma<<<gW, 256, 0, stream>>>(Xr16, Xi16, Z1r, Z1i, Z2r, Z2i,
                                        W1t, b1,
                                        Y1rb, Y1ib,
                                        Y1C8);

    // ---- Layer 2 ----
    spmm_k<<<N_NODES, 256, 0, stream>>>(cnt, ent, Y1C8, nullptr, nullptr,
                                        1.f, 0.f, Z1r, Z1i, Z1C8);
    spmm_k<<<N_NODES, 256, 0, stream>>>(cnt, ent, Z1C8, Y1rb, Y1ib,
                                        2.f, -1.f, Z2r, Z2i, nullptr);
    wapply_mfma<<<gW, 256, 0, stream>>>(Y1rb, Y1ib, Z1r, Z1i, Z2r, Z2i,
                                        W2t, b2,
                                        Y2rb, Y2ib,
                                        nullptr);

    // ---- Head ----
    head_mfma<<<64, 256, 0, stream>>>(Y2rb, Y2ib, Wcb, bc, out);
}